// Round 10
// baseline (72.099 us; speedup 1.0000x reference)
//
#include <hip/hip_runtime.h>

#define NB   4
#define SEQ  4096
#define CIN  128
#define C4D  32
#define OUTC 128
#define LOG2E 1.44269504f

typedef __attribute__((ext_vector_type(8))) short bf16x8;
typedef __attribute__((ext_vector_type(4))) float f32x4;

__device__ __forceinline__ short f2bf(float f) {
  union { float f; unsigned u; } v; v.f = f;
  unsigned r = v.u + 0x7FFFu + ((v.u >> 16) & 1u);
  return (short)(r >> 16);
}

__device__ __forceinline__ unsigned cvt_pk_bf16(float lo, float hi) {
  unsigned r;
  asm("v_cvt_pk_bf16_f32 %0, %1, %2" : "=v"(r) : "v"(lo), "v"(hi));
  return r;
}

__device__ __forceinline__ f32x4 mfma16(bf16x8 a, bf16x8 b, f32x4 c) {
  return __builtin_amdgcn_mfma_f32_16x16x32_bf16(a, b, c, 0, 0, 0);
}

// ---------------------------------------------------------------------------
// Kernel 1: fold value-path weights (unchanged).
// ---------------------------------------------------------------------------
__global__ void k_fuse(const float* __restrict__ wq, const float* __restrict__ wk,
                       const float* __restrict__ wv, const float* __restrict__ weight,
                       const float* __restrict__ bv,
                       short* __restrict__ wqb, short* __restrict__ wkb,
                       short* __restrict__ wfT, float* __restrict__ bfu) {
  int u = blockIdx.x, c = threadIdx.x;
  float acc = 0.f;
  for (int o = 0; o < OUTC; ++o) acc += wv[o * CIN + c] * weight[o * OUTC + u];
  wfT[u * CIN + c] = f2bf(acc);
  if (u < C4D) {
    wqb[u * CIN + c] = f2bf(wq[u * CIN + c]);
    wkb[u * CIN + c] = f2bf(wk[u * CIN + c]);
  }
  if (c == 0) {
    float a = 0.f;
    for (int o = 0; o < OUTC; ++o) a += bv[o] * weight[o * OUTC + u];
    bfu[u] = a;
  }
}

// ---------------------------------------------------------------------------
// Kernel 2: projections. K is stored pre-scaled by log2(e) so attention's
// softmax runs in the exp2 domain (native v_exp_f32, no mul).
// ---------------------------------------------------------------------------
__global__ __launch_bounds__(256) void k_proj(
    const float* __restrict__ x, const float* __restrict__ bq, const float* __restrict__ bk,
    const short* __restrict__ wqb, const short* __restrict__ wkb,
    const short* __restrict__ wfT, const float* __restrict__ bfu,
    short* __restrict__ ql, short* __restrict__ kb, short* __restrict__ vfb) {
  const int wid = threadIdx.x >> 6, lane = threadIdx.x & 63;
  const int lo = lane & 15, g = lane >> 4;
  const int p0 = blockIdx.x * 64 + wid * 16;

  f32x4 aq[2] = {}, ak[2] = {}, as_[8] = {};

#pragma unroll
  for (int kk = 0; kk < 4; ++kk) {
    const float* xp = x + (size_t)(p0 + lo) * CIN + kk * 32 + g * 8;
    float4 xa = *(const float4*)xp;
    float4 xb = *(const float4*)(xp + 4);
    bf16x8 af;
    af[0] = f2bf(xa.x); af[1] = f2bf(xa.y); af[2] = f2bf(xa.z); af[3] = f2bf(xa.w);
    af[4] = f2bf(xb.x); af[5] = f2bf(xb.y); af[6] = f2bf(xb.z); af[7] = f2bf(xb.w);
#pragma unroll
    for (int n = 0; n < 2; ++n) {
      bf16x8 bq_ = *(const bf16x8*)(wqb + (size_t)(n * 16 + lo) * CIN + kk * 32 + g * 8);
      aq[n] = mfma16(af, bq_, aq[n]);
      bf16x8 bk_ = *(const bf16x8*)(wkb + (size_t)(n * 16 + lo) * CIN + kk * 32 + g * 8);
      ak[n] = mfma16(af, bk_, ak[n]);
    }
#pragma unroll
    for (int n = 0; n < 8; ++n) {
      bf16x8 bs = *(const bf16x8*)(wfT + (size_t)(n * 16 + lo) * CIN + kk * 32 + g * 8);
      as_[n] = mfma16(af, bs, as_[n]);
    }
  }

#pragma unroll
  for (int n = 0; n < 2; ++n) {
    float bqv = bq[n * 16 + lo], bkv = bk[n * 16 + lo];
    int u = n * 16 + lo;
#pragma unroll
    for (int r = 0; r < 4; ++r) {
      int p = p0 + 4 * g + r;
      int bb = p >> 12, s = p & (SEQ - 1);
      ql[(size_t)bb * (SEQ * 32) + (size_t)(s >> 5) * 1024 + ((s >> 4) & 1) * 512 +
         (u >> 3) * 128 + (s & 15) * 8 + (u & 7)] = f2bf(aq[n][r] + bqv);
      kb[(size_t)p * C4D + u] = f2bf((ak[n][r] + bkv) * LOG2E);
    }
  }
  {
    const int p = p0 + 4 * g;          // r = 0; r=0..3 contiguous in VF
    const int bb = p >> 12, s = p & (SEQ - 1);
#pragma unroll
    for (int n = 0; n < 8; ++n) {
      int u = n * 16 + lo;
      float bvv = bfu[u];
      uint2 w;
      w.x = cvt_pk_bf16(as_[n][0] + bvv, as_[n][1] + bvv);
      w.y = cvt_pk_bf16(as_[n][2] + bvv, as_[n][3] + bvv);
      *(uint2*)&vfb[(size_t)bb * (SEQ * 128) + (size_t)(s >> 5) * 4096 + (u >> 4) * 512 +
                    ((s >> 2) & 3) * 128 + (u & 15) * 8 + ((s >> 4) & 1) * 4] = w;
    }
  }
}

// ---------------------------------------------------------------------------
// Kernel 3 (Design II + pipeline): wave = 64 i-rows (4 K-frags, o[4][8]),
// 8 waves, j-split 8, 16 iters. Q double-buffered in regs (prefetch t+1 at
// body top, before the rescale branch); V loaded into regs at body top so
// its latency hides under QK+softmax. exp2-domain softmax (K pre-scaled).
// Defer-max (THR=11.5 log2), deferred l-reduce, cvt_pk. LDS tree merge.
// ---------------------------------------------------------------------------
__global__ __launch_bounds__(512, 2) void k_attn(
    const short* __restrict__ ql, const short* __restrict__ kb,
    const short* __restrict__ vfb, const float* __restrict__ bias,
    float* __restrict__ out) {
  const int tid = threadIdx.x;
  const int wid = tid >> 6, lane = tid & 63;
  const int lo = lane & 15, g = lane >> 4;
  const int bid = blockIdx.x;
  const int xb = ((bid & 7) << 5) | (bid >> 3);   // 256 blocks, bijective
  const int b = xb >> 6;
  const int iw = (xb & 63) * 64;

  __shared__ float LDSF[33280];   // 4 slots x 8192 (O) + 4x64 (M) + 4x64 (L)

  const short* qB = ql + (size_t)b * (SEQ * 32) + (size_t)wid * 16384;
  const short* vB = vfb + (size_t)b * (SEQ * 128) + (size_t)wid * 65536;

  bf16x8 kf[4];
#pragma unroll
  for (int c = 0; c < 4; ++c)
    kf[c] = *(const bf16x8*)(kb + (size_t)(b * SEQ + iw + 16 * c + lo) * C4D + g * 8);

  f32x4 o[4][8];
#pragma unroll
  for (int c = 0; c < 4; ++c)
#pragma unroll
    for (int n = 0; n < 8; ++n) o[c][n] = (f32x4){0.f, 0.f, 0.f, 0.f};

  float ma[4] = {-3e38f, -3e38f, -3e38f, -3e38f};
  float la[4] = {0.f, 0.f, 0.f, 0.f};
  const f32x4 zf = {0.f, 0.f, 0.f, 0.f};

  bf16x8 pf[4];
  bf16x8 qb0[2], qb1[2];
  // prologue: Q tile 0
  qb0[0] = *(const bf16x8*)(qB + lane * 8);
  qb1[0] = *(const bf16x8*)(qB + 512 + lane * 8);

#pragma unroll 2
  for (int t = 0; t < 16; ++t) {
    const int cur = t & 1, nxt = cur ^ 1;

    // V for current tile: issue first, consumed after softmax (~500cy later)
    bf16x8 vfr[8];
    const short* vt = vB + t * 4096;
#pragma unroll
    for (int n = 0; n < 8; ++n)
      vfr[n] = *(const bf16x8*)(vt + n * 512 + lane * 8);

    // Q prefetch for next tile (head of next iter's dep chain)
    if (t + 1 < 16) {
      const short* qt = qB + (t + 1) * 1024;
      qb0[nxt] = *(const bf16x8*)(qt + lane * 8);
      qb1[nxt] = *(const bf16x8*)(qt + 512 + lane * 8);
    }

    f32x4 s0[4], s1[4];
    float tm[4];
#pragma unroll
    for (int c = 0; c < 4; ++c) {
      s0[c] = mfma16(qb0[cur], kf[c], zf);
      s1[c] = mfma16(qb1[cur], kf[c], zf);
      tm[c] = fmaxf(fmaxf(fmaxf(s0[c][0], s0[c][1]), fmaxf(s0[c][2], s0[c][3])),
                    fmaxf(fmaxf(s1[c][0], s1[c][1]), fmaxf(s1[c][2], s1[c][3])));
    }
    bool need = (tm[0] > ma[0] + 11.5f) | (tm[1] > ma[1] + 11.5f) |
                (tm[2] > ma[2] + 11.5f) | (tm[3] > ma[3] + 11.5f);
    if (__any(need)) {
#pragma unroll
      for (int c = 0; c < 4; ++c) {
        float rowm = fmaxf(tm[c], __shfl_xor(tm[c], 16, 64));
        rowm = fmaxf(rowm, __shfl_xor(rowm, 32, 64));
        float mnew = fmaxf(ma[c], rowm);
        float scale = exp2f(ma[c] - mnew);
        la[c] *= scale;
        float sc[4];
#pragma unroll
        for (int r = 0; r < 4; ++r) sc[r] = __shfl(scale, 4 * g + r, 64);
#pragma unroll
        for (int n = 0; n < 8; ++n)
#pragma unroll
          for (int r = 0; r < 4; ++r) o[c][n][r] *= sc[r];
        ma[c] = mnew;
      }
    }

#pragma unroll
    for (int c = 0; c < 4; ++c) {
      float p[8];
#pragma unroll
      for (int r = 0; r < 4; ++r) {
        p[r]     = exp2f(s0[c][r] - ma[c]);
        p[4 + r] = exp2f(s1[c][r] - ma[c]);
      }
      la[c] += (p[0] + p[1]) + (p[2] + p[3]) + ((p[4] + p[5]) + (p[6] + p[7]));
      union { bf16x8 v8; unsigned u[4]; } pk;
      pk.u[0] = cvt_pk_bf16(p[0], p[1]);
      pk.u[1] = cvt_pk_bf16(p[2], p[3]);
      pk.u[2] = cvt_pk_bf16(p[4], p[5]);
      pk.u[3] = cvt_pk_bf16(p[6], p[7]);
      pf[c] = pk.v8;
    }

#pragma unroll
    for (int n = 0; n < 8; ++n) {
      o[0][n] = mfma16(pf[0], vfr[n], o[0][n]);
      o[1][n] = mfma16(pf[1], vfr[n], o[1][n]);
      o[2][n] = mfma16(pf[2], vfr[n], o[2][n]);
      o[3][n] = mfma16(pf[3], vfr[n], o[3][n]);
    }
  }

  // deferred l-reduce over g (each g covered distinct j)
#pragma unroll
  for (int c = 0; c < 4; ++c) {
    la[c] += __shfl_xor(la[c], 16, 64);
    la[c] += __shfl_xor(la[c], 32, 64);
  }

  auto write_slot = [&](int s) {
    float* OSs = LDSF + s * 8192;
#pragma unroll
    for (int c = 0; c < 4; ++c)
#pragma unroll
      for (int n = 0; n < 8; ++n)
        *(f32x4*)&OSs[(c * 8 + n) * 256 + lane * 4] = o[c][n];
    if (lane < 16) {
#pragma unroll
      for (int c = 0; c < 4; ++c) {
        LDSF[32768 + s * 64 + c * 16 + lo] = ma[c];
        LDSF[33024 + s * 64 + c * 16 + lo] = la[c];
      }
    }
  };
  auto merge_slot = [&](int s) {
    float* OSs = LDSF + s * 8192;
#pragma unroll
    for (int c = 0; c < 4; ++c) {
      float ms = LDSF[32768 + s * 64 + c * 16 + lo];
      float ls = LDSF[33024 + s * 64 + c * 16 + lo];
      float M = fmaxf(ma[c], ms);
      float eo = exp2f(ma[c] - M), es = exp2f(ms - M);
      la[c] = eo * la[c] + es * ls;
      ma[c] = M;
      float eor[4], esr[4];
#pragma unroll
      for (int r = 0; r < 4; ++r) {
        eor[r] = __shfl(eo, 4 * g + r, 64);
        esr[r] = __shfl(es, 4 * g + r, 64);
      }
#pragma unroll
      for (int n = 0; n < 8; ++n) {
        f32x4 v = *(f32x4*)&OSs[(c * 8 + n) * 256 + lane * 4];
#pragma unroll
        for (int r = 0; r < 4; ++r)
          o[c][n][r] = eor[r] * o[c][n][r] + esr[r] * v[r];
      }
    }
  };

  if (wid >= 4) write_slot(wid - 4);
  __syncthreads();
  if (wid < 4) merge_slot(wid);
  __syncthreads();
  if (wid == 1) write_slot(0);
  if (wid == 3) write_slot(1);
  __syncthreads();
  if (wid == 0) merge_slot(0);
  if (wid == 2) merge_slot(1);
  __syncthreads();
  if (wid == 2) write_slot(0);
  __syncthreads();
  if (wid == 0) {
    merge_slot(0);
    float* outp = out + (size_t)(b * SEQ + iw) * OUTC;
#pragma unroll
    for (int c = 0; c < 4; ++c) {
      float ia = 1.f / la[c];
      float lir[4];
#pragma unroll
      for (int r = 0; r < 4; ++r) lir[r] = __shfl(ia, 4 * g + r, 64);
#pragma unroll
      for (int n = 0; n < 8; ++n) {
        float bu = bias[n * 16 + lo];
#pragma unroll
        for (int r = 0; r < 4; ++r)
          outp[(size_t)(c * 16 + 4 * g + r) * OUTC + n * 16 + lo] =
              o[c][n][r] * lir[r] + bu;
      }
    }
  }
}

// ---------------------------------------------------------------------------
extern "C" void kernel_launch(void* const* d_in, const int* in_sizes, int n_in,
                              void* d_out, int out_size, void* d_ws, size_t ws_size,
                              hipStream_t stream) {
  (void)in_sizes; (void)n_in; (void)out_size; (void)ws_size;
  const float* x      = (const float*)d_in[0];
  const float* weight = (const float*)d_in[1];
  const float* bias   = (const float*)d_in[2];
  const float* wq     = (const float*)d_in[3];
  const float* bq     = (const float*)d_in[4];
  const float* wk     = (const float*)d_in[5];
  const float* bk     = (const float*)d_in[6];
  const float* wv     = (const float*)d_in[7];
  const float* bv     = (const float*)d_in[8];
  float* out = (float*)d_out;

  char* ws = (char*)d_ws;
  short* kbuf = (short*)(ws);                                   // 1 MiB [p][32]
  short* vfb  = (short*)(ws + ((size_t)1 << 20));               // 4 MiB VF tiles
  short* qlb  = (short*)(ws + ((size_t)5 << 20));               // 1 MiB QL tiles
  short* wqb  = (short*)(ws + ((size_t)6 << 20));               // 8 KiB
  short* wkb  = (short*)(ws + ((size_t)6 << 20) + 8192);        // 8 KiB
  short* wfT  = (short*)(ws + ((size_t)6 << 20) + 16384);       // 32 KiB
  float* bfu  = (float*)(ws + ((size_t)6 << 20) + 49152);       // 512 B

  hipLaunchKernelGGL(k_fuse, dim3(OUTC), dim3(CIN), 0, stream,
                     wq, wk, wv, weight, bv, wqb, wkb, wfT, bfu);
  hipLaunchKernelGGL(k_proj, dim3(NB * SEQ / 64), dim3(256), 0, stream,
                     x, bq, bk, wqb, wkb, wfT, bfu, qlb, kbuf, vfb);
  hipLaunchKernelGGL(k_attn, dim3(NB * SEQ / 64), dim3(512), 0, stream,
                     qlb, kbuf, vfb, bias, out);
}

// Round 11
// 65.677 us; speedup vs baseline: 1.0978x; 1.0978x over previous
//
#include <hip/hip_runtime.h>

#define NB   4
#define SEQ  4096
#define CIN  128
#define C4D  32
#define OUTC 128
#define LOG2E 1.44269504f

typedef __attribute__((ext_vector_type(8))) short bf16x8;
typedef __attribute__((ext_vector_type(4))) float f32x4;

__device__ __forceinline__ short f2bf(float f) {
  union { float f; unsigned u; } v; v.f = f;
  unsigned r = v.u + 0x7FFFu + ((v.u >> 16) & 1u);
  return (short)(r >> 16);
}

__device__ __forceinline__ unsigned cvt_pk_bf16(float lo, float hi) {
  unsigned r;
  asm("v_cvt_pk_bf16_f32 %0, %1, %2" : "=v"(r) : "v"(lo), "v"(hi));
  return r;
}

__device__ __forceinline__ f32x4 mfma16(bf16x8 a, bf16x8 b, f32x4 c) {
  return __builtin_amdgcn_mfma_f32_16x16x32_bf16(a, b, c, 0, 0, 0);
}

// async 16B/lane global->LDS: per-lane global src, wave-uniform LDS base
// (HW writes base + lane*16).
__device__ __forceinline__ void gload_lds16(const short* g, short* l) {
  __builtin_amdgcn_global_load_lds(
      (const __attribute__((address_space(1))) void*)(g),
      (__attribute__((address_space(3))) void*)(l), 16, 0, 0);
}

// ---------------------------------------------------------------------------
// Kernel 1: fold value-path weights (unchanged).
// ---------------------------------------------------------------------------
__global__ void k_fuse(const float* __restrict__ wq, const float* __restrict__ wk,
                       const float* __restrict__ wv, const float* __restrict__ weight,
                       const float* __restrict__ bv,
                       short* __restrict__ wqb, short* __restrict__ wkb,
                       short* __restrict__ wfT, float* __restrict__ bfu) {
  int u = blockIdx.x, c = threadIdx.x;
  float acc = 0.f;
  for (int o = 0; o < OUTC; ++o) acc += wv[o * CIN + c] * weight[o * OUTC + u];
  wfT[u * CIN + c] = f2bf(acc);
  if (u < C4D) {
    wqb[u * CIN + c] = f2bf(wq[u * CIN + c]);
    wkb[u * CIN + c] = f2bf(wk[u * CIN + c]);
  }
  if (c == 0) {
    float a = 0.f;
    for (int o = 0; o < OUTC; ++o) a += bv[o] * weight[o * OUTC + u];
    bfu[u] = a;
  }
}

// ---------------------------------------------------------------------------
// Kernel 2: projections (unchanged from R10). K pre-scaled by log2(e).
// ---------------------------------------------------------------------------
__global__ __launch_bounds__(256) void k_proj(
    const float* __restrict__ x, const float* __restrict__ bq, const float* __restrict__ bk,
    const short* __restrict__ wqb, const short* __restrict__ wkb,
    const short* __restrict__ wfT, const float* __restrict__ bfu,
    short* __restrict__ ql, short* __restrict__ kb, short* __restrict__ vfb) {
  const int wid = threadIdx.x >> 6, lane = threadIdx.x & 63;
  const int lo = lane & 15, g = lane >> 4;
  const int p0 = blockIdx.x * 64 + wid * 16;

  f32x4 aq[2] = {}, ak[2] = {}, as_[8] = {};

#pragma unroll
  for (int kk = 0; kk < 4; ++kk) {
    const float* xp = x + (size_t)(p0 + lo) * CIN + kk * 32 + g * 8;
    float4 xa = *(const float4*)xp;
    float4 xb = *(const float4*)(xp + 4);
    bf16x8 af;
    af[0] = f2bf(xa.x); af[1] = f2bf(xa.y); af[2] = f2bf(xa.z); af[3] = f2bf(xa.w);
    af[4] = f2bf(xb.x); af[5] = f2bf(xb.y); af[6] = f2bf(xb.z); af[7] = f2bf(xb.w);
#pragma unroll
    for (int n = 0; n < 2; ++n) {
      bf16x8 bq_ = *(const bf16x8*)(wqb + (size_t)(n * 16 + lo) * CIN + kk * 32 + g * 8);
      aq[n] = mfma16(af, bq_, aq[n]);
      bf16x8 bk_ = *(const bf16x8*)(wkb + (size_t)(n * 16 + lo) * CIN + kk * 32 + g * 8);
      ak[n] = mfma16(af, bk_, ak[n]);
    }
#pragma unroll
    for (int n = 0; n < 8; ++n) {
      bf16x8 bs = *(const bf16x8*)(wfT + (size_t)(n * 16 + lo) * CIN + kk * 32 + g * 8);
      as_[n] = mfma16(af, bs, as_[n]);
    }
  }

#pragma unroll
  for (int n = 0; n < 2; ++n) {
    float bqv = bq[n * 16 + lo], bkv = bk[n * 16 + lo];
    int u = n * 16 + lo;
#pragma unroll
    for (int r = 0; r < 4; ++r) {
      int p = p0 + 4 * g + r;
      int bb = p >> 12, s = p & (SEQ - 1);
      ql[(size_t)bb * (SEQ * 32) + (size_t)(s >> 5) * 1024 + ((s >> 4) & 1) * 512 +
         (u >> 3) * 128 + (s & 15) * 8 + (u & 7)] = f2bf(aq[n][r] + bqv);
      kb[(size_t)p * C4D + u] = f2bf((ak[n][r] + bkv) * LOG2E);
    }
  }
  {
    const int p = p0 + 4 * g;          // r = 0; r=0..3 contiguous in VF
    const int bb = p >> 12, s = p & (SEQ - 1);
#pragma unroll
    for (int n = 0; n < 8; ++n) {
      int u = n * 16 + lo;
      float bvv = bfu[u];
      uint2 w;
      w.x = cvt_pk_bf16(as_[n][0] + bvv, as_[n][1] + bvv);
      w.y = cvt_pk_bf16(as_[n][2] + bvv, as_[n][3] + bvv);
      *(uint2*)&vfb[(size_t)bb * (SEQ * 128) + (size_t)(s >> 5) * 4096 + (u >> 4) * 512 +
                    ((s >> 2) & 3) * 128 + (u & 15) * 8 + ((s >> 4) & 1) * 4] = w;
    }
  }
}

// ---------------------------------------------------------------------------
// Kernel 3 (Design II + LDS-staged V): wave = 64 i-rows (4 K-frags, o[4][8]),
// 8 waves, j-split 8, 16 iters. V tile t+1 staged via global_load_lds into a
// per-wave private double-buffered LDS region (no barriers, no VGPR cost);
// PV reads it with ds_read_b128. Q reloads into the same regs after QK (WAR).
// exp2-domain defer-max softmax, deferred l-reduce, cvt_pk. LDS tree merge
// overlays the staging region after a barrier.
// ---------------------------------------------------------------------------
__global__ __launch_bounds__(512, 2) void k_attn(
    const short* __restrict__ ql, const short* __restrict__ kb,
    const short* __restrict__ vfb, const float* __restrict__ bias,
    float* __restrict__ out) {
  const int tid = threadIdx.x;
  const int wid = tid >> 6, lane = tid & 63;
  const int lo = lane & 15, g = lane >> 4;
  const int bid = blockIdx.x;
  const int xb = ((bid & 7) << 5) | (bid >> 3);   // 256 blocks, bijective
  const int b = xb >> 6;
  const int iw = (xb & 63) * 64;

  __shared__ __align__(16) char smem[133120];
  short* Vs = (short*)smem;          // staging: 8 waves x 2 bufs x 4096 shorts
  float* LDSF = (float*)smem;        // merge overlay (after barrier)

  const short* qB = ql + (size_t)b * (SEQ * 32) + (size_t)wid * 16384;
  const short* vB = vfb + (size_t)b * (SEQ * 128) + (size_t)wid * 65536;
  short* Vw = Vs + wid * 8192;       // this wave's staging region

  bf16x8 kf[4];
#pragma unroll
  for (int c = 0; c < 4; ++c)
    kf[c] = *(const bf16x8*)(kb + (size_t)(b * SEQ + iw + 16 * c + lo) * C4D + g * 8);

  f32x4 o[4][8];
#pragma unroll
  for (int c = 0; c < 4; ++c)
#pragma unroll
    for (int n = 0; n < 8; ++n) o[c][n] = (f32x4){0.f, 0.f, 0.f, 0.f};

  float ma[4] = {-3e38f, -3e38f, -3e38f, -3e38f};
  float la[4] = {0.f, 0.f, 0.f, 0.f};
  const f32x4 zf = {0.f, 0.f, 0.f, 0.f};

  bf16x8 pf[4];

  // prologue: stage V tile 0 into buf 0, then load Q tile 0 (Q is newest ->
  // compiler's vmcnt wait for Q also drains the V stage).
#pragma unroll
  for (int n = 0; n < 8; ++n)
    gload_lds16(vB + n * 512 + lane * 8, Vw + n * 512);
  bf16x8 qf0 = *(const bf16x8*)(qB + lane * 8);
  bf16x8 qf1 = *(const bf16x8*)(qB + 512 + lane * 8);

#pragma unroll 2
  for (int t = 0; t < 16; ++t) {
    const int cur = t & 1, nxt = cur ^ 1;

    // QK (waits on qf regs -> vmcnt(0) -> V_t staging complete too)
    f32x4 s0[4], s1[4];
    float tm[4];
#pragma unroll
    for (int c = 0; c < 4; ++c) {
      s0[c] = mfma16(qf0, kf[c], zf);
      s1[c] = mfma16(qf1, kf[c], zf);
      tm[c] = fmaxf(fmaxf(fmaxf(s0[c][0], s0[c][1]), fmaxf(s0[c][2], s0[c][3])),
                    fmaxf(fmaxf(s1[c][0], s1[c][1]), fmaxf(s1[c][2], s1[c][3])));
    }

    // stage V tile t+1 (async, per-wave private buffer, no barrier)
    if (t + 1 < 16) {
      const short* vn = vB + (size_t)(t + 1) * 4096;
      short* vd = Vw + nxt * 4096;
#pragma unroll
      for (int n = 0; n < 8; ++n)
        gload_lds16(vn + n * 512 + lane * 8, vd + n * 512);
      // Q reload for t+1 into the same regs (WAR on the QK MFMA reads)
      const short* qt = qB + (size_t)(t + 1) * 1024;
      qf0 = *(const bf16x8*)(qt + lane * 8);
      qf1 = *(const bf16x8*)(qt + 512 + lane * 8);
    }

    bool need = (tm[0] > ma[0] + 11.5f) | (tm[1] > ma[1] + 11.5f) |
                (tm[2] > ma[2] + 11.5f) | (tm[3] > ma[3] + 11.5f);
    if (__any(need)) {
#pragma unroll
      for (int c = 0; c < 4; ++c) {
        float rowm = fmaxf(tm[c], __shfl_xor(tm[c], 16, 64));
        rowm = fmaxf(rowm, __shfl_xor(rowm, 32, 64));
        float mnew = fmaxf(ma[c], rowm);
        float scale = exp2f(ma[c] - mnew);
        la[c] *= scale;
        float sc[4];
#pragma unroll
        for (int r = 0; r < 4; ++r) sc[r] = __shfl(scale, 4 * g + r, 64);
#pragma unroll
        for (int n = 0; n < 8; ++n)
#pragma unroll
          for (int r = 0; r < 4; ++r) o[c][n][r] *= sc[r];
        ma[c] = mnew;
      }
    }

#pragma unroll
    for (int c = 0; c < 4; ++c) {
      float p[8];
#pragma unroll
      for (int r = 0; r < 4; ++r) {
        p[r]     = exp2f(s0[c][r] - ma[c]);
        p[4 + r] = exp2f(s1[c][r] - ma[c]);
      }
      la[c] += (p[0] + p[1]) + (p[2] + p[3]) + ((p[4] + p[5]) + (p[6] + p[7]));
      union { bf16x8 v8; unsigned u[4]; } pk;
      pk.u[0] = cvt_pk_bf16(p[0], p[1]);
      pk.u[1] = cvt_pk_bf16(p[2], p[3]);
      pk.u[2] = cvt_pk_bf16(p[4], p[5]);
      pk.u[3] = cvt_pk_bf16(p[6], p[7]);
      pf[c] = pk.v8;
    }

    // V_t is safely landed when <=10 newest VMEM ops (8 V_{t+1} + 2 Q_{t+1})
    // remain outstanding; ordered vs the ds_reads by the memory clobber.
    asm volatile("s_waitcnt vmcnt(10)" ::: "memory");

    const short* vt = Vw + cur * 4096;
#pragma unroll
    for (int n = 0; n < 8; ++n) {
      bf16x8 vfr = *(const bf16x8*)(vt + n * 512 + lane * 8);
      o[0][n] = mfma16(pf[0], vfr, o[0][n]);
      o[1][n] = mfma16(pf[1], vfr, o[1][n]);
      o[2][n] = mfma16(pf[2], vfr, o[2][n]);
      o[3][n] = mfma16(pf[3], vfr, o[3][n]);
    }
  }

  // deferred l-reduce over g (each g covered distinct j)
#pragma unroll
  for (int c = 0; c < 4; ++c) {
    la[c] += __shfl_xor(la[c], 16, 64);
    la[c] += __shfl_xor(la[c], 32, 64);
  }

  __syncthreads();   // staging region dead; safe to overlay merge arrays

  auto write_slot = [&](int s) {
    float* OSs = LDSF + s * 8192;
#pragma unroll
    for (int c = 0; c < 4; ++c)
#pragma unroll
      for (int n = 0; n < 8; ++n)
        *(f32x4*)&OSs[(c * 8 + n) * 256 + lane * 4] = o[c][n];
    if (lane < 16) {
#pragma unroll
      for (int c = 0; c < 4; ++c) {
        LDSF[32768 + s * 64 + c * 16 + lo] = ma[c];
        LDSF[33024 + s * 64 + c * 16 + lo] = la[c];
      }
    }
  };
  auto merge_slot = [&](int s) {
    float* OSs = LDSF + s * 8192;
#pragma unroll
    for (int c = 0; c < 4; ++c) {
      float ms = LDSF[32768 + s * 64 + c * 16 + lo];
      float ls = LDSF[33024 + s * 64 + c * 16 + lo];
      float M = fmaxf(ma[c], ms);
      float eo = exp2f(ma[c] - M), es = exp2f(ms - M);
      la[c] = eo * la[c] + es * ls;
      ma[c] = M;
      float eor[4], esr[4];
#pragma unroll
      for (int r = 0; r < 4; ++r) {
        eor[r] = __shfl(eo, 4 * g + r, 64);
        esr[r] = __shfl(es, 4 * g + r, 64);
      }
#pragma unroll
      for (int n = 0; n < 8; ++n) {
        f32x4 v = *(f32x4*)&OSs[(c * 8 + n) * 256 + lane * 4];
#pragma unroll
        for (int r = 0; r < 4; ++r)
          o[c][n][r] = eor[r] * o[c][n][r] + esr[r] * v[r];
      }
    }
  };

  if (wid >= 4) write_slot(wid - 4);
  __syncthreads();
  if (wid < 4) merge_slot(wid);
  __syncthreads();
  if (wid == 1) write_slot(0);
  if (wid == 3) write_slot(1);
  __syncthreads();
  if (wid == 0) merge_slot(0);
  if (wid == 2) merge_slot(1);
  __syncthreads();
  if (wid == 2) write_slot(0);
  __syncthreads();
  if (wid == 0) {
    merge_slot(0);
    float* outp = out + (size_t)(b * SEQ + iw) * OUTC;
#pragma unroll
    for (int c = 0; c < 4; ++c) {
      float ia = 1.f / la[c];
      float lir[4];
#pragma unroll
      for (int r = 0; r < 4; ++r) lir[r] = __shfl(ia, 4 * g + r, 64);
#pragma unroll
      for (int n = 0; n < 8; ++n) {
        float bu = bias[n * 16 + lo];
#pragma unroll
        for (int r = 0; r < 4; ++r)
          outp[(size_t)(c * 16 + 4 * g + r) * OUTC + n * 16 + lo] =
              o[c][n][r] * lir[r] + bu;
      }
    }
  }
}

// ---------------------------------------------------------------------------
extern "C" void kernel_launch(void* const* d_in, const int* in_sizes, int n_in,
                              void* d_out, int out_size, void* d_ws, size_t ws_size,
                              hipStream_t stream) {
  (void)in_sizes; (void)n_in; (void)out_size; (void)ws_size;
  const float* x      = (const float*)d_in[0];
  const float* weight = (const float*)d_in[1];
  const float* bias   = (const float*)d_in[2];
  const float* wq     = (const float*)d_in[3];
  const float* bq     = (const float*)d_in[4];
  const float* wk     = (const float*)d_in[5];
  const float* bk     = (const float*)d_in[6];
  const float* wv     = (const float*)d_in[7];
  const float* bv     = (const float*)d_in[8];
  float* out = (float*)d_out;

  char* ws = (char*)d_ws;
  short* kbuf = (short*)(ws);                                   // 1 MiB [p][32]
  short* vfb  = (short*)(ws + ((size_t)1 << 20));               // 4 MiB VF tiles
  short* qlb  = (short*)(ws + ((size_t)5 << 20));               // 1 MiB QL tiles
  short* wqb  = (short*)(ws + ((size_t)6 << 20));               // 8 KiB
  short* wkb  = (short*)(ws + ((size_t)6 << 20) + 8192);        // 8 KiB
  short* wfT  = (short*)(ws + ((size_t)6 << 20) + 16384);       // 32 KiB
  float* bfu  = (float*)(ws + ((size_t)6 << 20) + 49152);       // 512 B

  hipLaunchKernelGGL(k_fuse, dim3(OUTC), dim3(CIN), 0, stream,
                     wq, wk, wv, weight, bv, wqb, wkb, wfT, bfu);
  hipLaunchKernelGGL(k_proj, dim3(NB * SEQ / 64), dim3(256), 0, stream,
                     x, bq, bk, wqb, wkb, wfT, bfu, qlb, kbuf, vfb);
  hipLaunchKernelGGL(k_attn, dim3(NB * SEQ / 64), dim3(512), 0, stream,
                     qlb, kbuf, vfb, bias, out);
}

// Round 12
// 58.670 us; speedup vs baseline: 1.2289x; 1.1194x over previous
//
#include <hip/hip_runtime.h>

#define NB   4
#define SEQ  4096
#define CIN  128
#define C4D  32
#define OUTC 128
#define LOG2E 1.44269504f

typedef __attribute__((ext_vector_type(8))) short bf16x8;
typedef __attribute__((ext_vector_type(4))) float f32x4;

__device__ __forceinline__ short f2bf(float f) {
  union { float f; unsigned u; } v; v.f = f;
  unsigned r = v.u + 0x7FFFu + ((v.u >> 16) & 1u);
  return (short)(r >> 16);
}

__device__ __forceinline__ unsigned cvt_pk_bf16(float lo, float hi) {
  unsigned r;
  asm("v_cvt_pk_bf16_f32 %0, %1, %2" : "=v"(r) : "v"(lo), "v"(hi));
  return r;
}

// native 2^x (v_exp_f32) — exp2f() without fast-math lowers to the slow
// precise OCML sequence; this is the single-instruction form.
__device__ __forceinline__ float fast_exp2(float x) {
  float r;
  asm("v_exp_f32 %0, %1" : "=v"(r) : "v"(x));
  return r;
}

__device__ __forceinline__ f32x4 mfma16(bf16x8 a, bf16x8 b, f32x4 c) {
  return __builtin_amdgcn_mfma_f32_16x16x32_bf16(a, b, c, 0, 0, 0);
}

// async 16B/lane global->LDS: per-lane global src, wave-uniform LDS base
// (HW writes base + lane*16).
__device__ __forceinline__ void gload_lds16(const short* g, short* l) {
  __builtin_amdgcn_global_load_lds(
      (const __attribute__((address_space(1))) void*)(g),
      (__attribute__((address_space(3))) void*)(l), 16, 0, 0);
}

// ---------------------------------------------------------------------------
// Kernel 1: fold value-path weights (unchanged).
// ---------------------------------------------------------------------------
__global__ void k_fuse(const float* __restrict__ wq, const float* __restrict__ wk,
                       const float* __restrict__ wv, const float* __restrict__ weight,
                       const float* __restrict__ bv,
                       short* __restrict__ wqb, short* __restrict__ wkb,
                       short* __restrict__ wfT, float* __restrict__ bfu) {
  int u = blockIdx.x, c = threadIdx.x;
  float acc = 0.f;
  for (int o = 0; o < OUTC; ++o) acc += wv[o * CIN + c] * weight[o * OUTC + u];
  wfT[u * CIN + c] = f2bf(acc);
  if (u < C4D) {
    wqb[u * CIN + c] = f2bf(wq[u * CIN + c]);
    wkb[u * CIN + c] = f2bf(wk[u * CIN + c]);
  }
  if (c == 0) {
    float a = 0.f;
    for (int o = 0; o < OUTC; ++o) a += bv[o] * weight[o * OUTC + u];
    bfu[u] = a;
  }
}

// ---------------------------------------------------------------------------
// Kernel 2: projections (unchanged from R11). K pre-scaled by log2(e).
// ---------------------------------------------------------------------------
__global__ __launch_bounds__(256) void k_proj(
    const float* __restrict__ x, const float* __restrict__ bq, const float* __restrict__ bk,
    const short* __restrict__ wqb, const short* __restrict__ wkb,
    const short* __restrict__ wfT, const float* __restrict__ bfu,
    short* __restrict__ ql, short* __restrict__ kb, short* __restrict__ vfb) {
  const int wid = threadIdx.x >> 6, lane = threadIdx.x & 63;
  const int lo = lane & 15, g = lane >> 4;
  const int p0 = blockIdx.x * 64 + wid * 16;

  f32x4 aq[2] = {}, ak[2] = {}, as_[8] = {};

#pragma unroll
  for (int kk = 0; kk < 4; ++kk) {
    const float* xp = x + (size_t)(p0 + lo) * CIN + kk * 32 + g * 8;
    float4 xa = *(const float4*)xp;
    float4 xb = *(const float4*)(xp + 4);
    bf16x8 af;
    af[0] = f2bf(xa.x); af[1] = f2bf(xa.y); af[2] = f2bf(xa.z); af[3] = f2bf(xa.w);
    af[4] = f2bf(xb.x); af[5] = f2bf(xb.y); af[6] = f2bf(xb.z); af[7] = f2bf(xb.w);
#pragma unroll
    for (int n = 0; n < 2; ++n) {
      bf16x8 bq_ = *(const bf16x8*)(wqb + (size_t)(n * 16 + lo) * CIN + kk * 32 + g * 8);
      aq[n] = mfma16(af, bq_, aq[n]);
      bf16x8 bk_ = *(const bf16x8*)(wkb + (size_t)(n * 16 + lo) * CIN + kk * 32 + g * 8);
      ak[n] = mfma16(af, bk_, ak[n]);
    }
#pragma unroll
    for (int n = 0; n < 8; ++n) {
      bf16x8 bs = *(const bf16x8*)(wfT + (size_t)(n * 16 + lo) * CIN + kk * 32 + g * 8);
      as_[n] = mfma16(af, bs, as_[n]);
    }
  }

#pragma unroll
  for (int n = 0; n < 2; ++n) {
    float bqv = bq[n * 16 + lo], bkv = bk[n * 16 + lo];
    int u = n * 16 + lo;
#pragma unroll
    for (int r = 0; r < 4; ++r) {
      int p = p0 + 4 * g + r;
      int bb = p >> 12, s = p & (SEQ - 1);
      ql[(size_t)bb * (SEQ * 32) + (size_t)(s >> 5) * 1024 + ((s >> 4) & 1) * 512 +
         (u >> 3) * 128 + (s & 15) * 8 + (u & 7)] = f2bf(aq[n][r] + bqv);
      kb[(size_t)p * C4D + u] = f2bf((ak[n][r] + bkv) * LOG2E);
    }
  }
  {
    const int p = p0 + 4 * g;          // r = 0; r=0..3 contiguous in VF
    const int bb = p >> 12, s = p & (SEQ - 1);
#pragma unroll
    for (int n = 0; n < 8; ++n) {
      int u = n * 16 + lo;
      float bvv = bfu[u];
      uint2 w;
      w.x = cvt_pk_bf16(as_[n][0] + bvv, as_[n][1] + bvv);
      w.y = cvt_pk_bf16(as_[n][2] + bvv, as_[n][3] + bvv);
      *(uint2*)&vfb[(size_t)bb * (SEQ * 128) + (size_t)(s >> 5) * 4096 + (u >> 4) * 512 +
                    ((s >> 2) & 3) * 128 + (u & 15) * 8 + ((s >> 4) & 1) * 4] = w;
    }
  }
}

// ---------------------------------------------------------------------------
// Kernel 3 (Design II + LDS-staged V, fixed pipeline): wave = 64 i-rows,
// 8 waves, j-split 8, 16 iters. Per iter: QK -> [Q_{t+1} loads FIRST, then
// V_{t+1} gload_lds] -> softmax (native v_exp_f32) -> vmcnt(10) -> PV from
// LDS. Q-first issue order means QK_t's register wait is vmcnt(8), leaving
// V_t staging in flight across QK+softmax. Defer-max, deferred l-reduce,
// cvt_pk. LDS tree merge overlays staging region after a barrier.
// ---------------------------------------------------------------------------
__global__ __launch_bounds__(512, 2) void k_attn(
    const short* __restrict__ ql, const short* __restrict__ kb,
    const short* __restrict__ vfb, const float* __restrict__ bias,
    float* __restrict__ out) {
  const int tid = threadIdx.x;
  const int wid = tid >> 6, lane = tid & 63;
  const int lo = lane & 15, g = lane >> 4;
  const int bid = blockIdx.x;
  const int xb = ((bid & 7) << 5) | (bid >> 3);   // 256 blocks, bijective
  const int b = xb >> 6;
  const int iw = (xb & 63) * 64;

  __shared__ __align__(16) char smem[133120];
  short* Vs = (short*)smem;          // staging: 8 waves x 2 bufs x 4096 shorts
  float* LDSF = (float*)smem;        // merge overlay (after barrier)

  const short* qB = ql + (size_t)b * (SEQ * 32) + (size_t)wid * 16384;
  const short* vB = vfb + (size_t)b * (SEQ * 128) + (size_t)wid * 65536;
  short* Vw = Vs + wid * 8192;       // this wave's staging region

  bf16x8 kf[4];
#pragma unroll
  for (int c = 0; c < 4; ++c)
    kf[c] = *(const bf16x8*)(kb + (size_t)(b * SEQ + iw + 16 * c + lo) * C4D + g * 8);

  f32x4 o[4][8];
#pragma unroll
  for (int c = 0; c < 4; ++c)
#pragma unroll
    for (int n = 0; n < 8; ++n) o[c][n] = (f32x4){0.f, 0.f, 0.f, 0.f};

  float ma[4] = {-3e38f, -3e38f, -3e38f, -3e38f};
  float la[4] = {0.f, 0.f, 0.f, 0.f};
  const f32x4 zf = {0.f, 0.f, 0.f, 0.f};

  bf16x8 pf[4];

  // prologue: Q tile 0 first, then stage V tile 0 (QK_0 waits vmcnt(8)).
  bf16x8 qf0 = *(const bf16x8*)(qB + lane * 8);
  bf16x8 qf1 = *(const bf16x8*)(qB + 512 + lane * 8);
#pragma unroll
  for (int n = 0; n < 8; ++n)
    gload_lds16(vB + n * 512 + lane * 8, Vw + n * 512);

#pragma unroll 2
  for (int t = 0; t < 16; ++t) {
    const int cur = t & 1, nxt = cur ^ 1;

    // QK (waits only on qf regs: vmcnt(8) -> V_t staging still in flight)
    f32x4 s0[4], s1[4];
    float tm[4];
#pragma unroll
    for (int c = 0; c < 4; ++c) {
      s0[c] = mfma16(qf0, kf[c], zf);
      s1[c] = mfma16(qf1, kf[c], zf);
      tm[c] = fmaxf(fmaxf(fmaxf(s0[c][0], s0[c][1]), fmaxf(s0[c][2], s0[c][3])),
                    fmaxf(fmaxf(s1[c][0], s1[c][1]), fmaxf(s1[c][2], s1[c][3])));
    }

    // prefetch t+1: Q FIRST (so future QK waits vmcnt(8), not 0), V after.
    if (t + 1 < 16) {
      const short* qt = qB + (size_t)(t + 1) * 1024;
      qf0 = *(const bf16x8*)(qt + lane * 8);
      qf1 = *(const bf16x8*)(qt + 512 + lane * 8);
      const short* vn = vB + (size_t)(t + 1) * 4096;
      short* vd = Vw + nxt * 4096;
#pragma unroll
      for (int n = 0; n < 8; ++n)
        gload_lds16(vn + n * 512 + lane * 8, vd + n * 512);
    }

    bool need = (tm[0] > ma[0] + 11.5f) | (tm[1] > ma[1] + 11.5f) |
                (tm[2] > ma[2] + 11.5f) | (tm[3] > ma[3] + 11.5f);
    if (__any(need)) {
#pragma unroll
      for (int c = 0; c < 4; ++c) {
        float rowm = fmaxf(tm[c], __shfl_xor(tm[c], 16, 64));
        rowm = fmaxf(rowm, __shfl_xor(rowm, 32, 64));
        float mnew = fmaxf(ma[c], rowm);
        float scale = fast_exp2(ma[c] - mnew);
        la[c] *= scale;
        float sc[4];
#pragma unroll
        for (int r = 0; r < 4; ++r) sc[r] = __shfl(scale, 4 * g + r, 64);
#pragma unroll
        for (int n = 0; n < 8; ++n)
#pragma unroll
          for (int r = 0; r < 4; ++r) o[c][n][r] *= sc[r];
        ma[c] = mnew;
      }
    }

#pragma unroll
    for (int c = 0; c < 4; ++c) {
      float p[8];
#pragma unroll
      for (int r = 0; r < 4; ++r) {
        p[r]     = fast_exp2(s0[c][r] - ma[c]);
        p[4 + r] = fast_exp2(s1[c][r] - ma[c]);
      }
      la[c] += (p[0] + p[1]) + (p[2] + p[3]) + ((p[4] + p[5]) + (p[6] + p[7]));
      union { bf16x8 v8; unsigned u[4]; } pk;
      pk.u[0] = cvt_pk_bf16(p[0], p[1]);
      pk.u[1] = cvt_pk_bf16(p[2], p[3]);
      pk.u[2] = cvt_pk_bf16(p[4], p[5]);
      pk.u[3] = cvt_pk_bf16(p[6], p[7]);
      pf[c] = pk.v8;
    }

    // V_t landed when <=10 newest VMEM ops (2 Q_{t+1} + 8 V_{t+1}) remain.
    asm volatile("s_waitcnt vmcnt(10)" ::: "memory");

    const short* vt = Vw + cur * 4096;
#pragma unroll
    for (int n = 0; n < 8; ++n) {
      bf16x8 vfr = *(const bf16x8*)(vt + n * 512 + lane * 8);
      o[0][n] = mfma16(pf[0], vfr, o[0][n]);
      o[1][n] = mfma16(pf[1], vfr, o[1][n]);
      o[2][n] = mfma16(pf[2], vfr, o[2][n]);
      o[3][n] = mfma16(pf[3], vfr, o[3][n]);
    }
  }

  // deferred l-reduce over g (each g covered distinct j)
#pragma unroll
  for (int c = 0; c < 4; ++c) {
    la[c] += __shfl_xor(la[c], 16, 64);
    la[c] += __shfl_xor(la[c], 32, 64);
  }

  __syncthreads();   // staging region dead; safe to overlay merge arrays

  auto write_slot = [&](int s) {
    float* OSs = LDSF + s * 8192;
#pragma unroll
    for (int c = 0; c < 4; ++c)
#pragma unroll
      for (int n = 0; n < 8; ++n)
        *(f32x4*)&OSs[(c * 8 + n) * 256 + lane * 4] = o[c][n];
    if (lane < 16) {
#pragma unroll
      for (int c = 0; c < 4; ++c) {
        LDSF[32768 + s * 64 + c * 16 + lo] = ma[c];
        LDSF[33024 + s * 64 + c * 16 + lo] = la[c];
      }
    }
  };
  auto merge_slot = [&](int s) {
    float* OSs = LDSF + s * 8192;
#pragma unroll
    for (int c = 0; c < 4; ++c) {
      float ms = LDSF[32768 + s * 64 + c * 16 + lo];
      float ls = LDSF[33024 + s * 64 + c * 16 + lo];
      float M = fmaxf(ma[c], ms);
      float eo = fast_exp2(ma[c] - M), es = fast_exp2(ms - M);
      la[c] = eo * la[c] + es * ls;
      ma[c] = M;
      float eor[4], esr[4];
#pragma unroll
      for (int r = 0; r < 4; ++r) {
        eor[r] = __shfl(eo, 4 * g + r, 64);
        esr[r] = __shfl(es, 4 * g + r, 64);
      }
#pragma unroll
      for (int n = 0; n < 8; ++n) {
        f32x4 v = *(f32x4*)&OSs[(c * 8 + n) * 256 + lane * 4];
#pragma unroll
        for (int r = 0; r < 4; ++r)
          o[c][n][r] = eor[r] * o[c][n][r] + esr[r] * v[r];
      }
    }
  };

  if (wid >= 4) write_slot(wid - 4);
  __syncthreads();
  if (wid < 4) merge_slot(wid);
  __syncthreads();
  if (wid == 1) write_slot(0);
  if (wid == 3) write_slot(1);
  __syncthreads();
  if (wid == 0) merge_slot(0);
  if (wid == 2) merge_slot(1);
  __syncthreads();
  if (wid == 2) write_slot(0);
  __syncthreads();
  if (wid == 0) {
    merge_slot(0);
    float* outp = out + (size_t)(b * SEQ + iw) * OUTC;
#pragma unroll
    for (int c = 0; c < 4; ++c) {
      float ia = 1.f / la[c];
      float lir[4];
#pragma unroll
      for (int r = 0; r < 4; ++r) lir[r] = __shfl(ia, 4 * g + r, 64);
#pragma unroll
      for (int n = 0; n < 8; ++n) {
        float bu = bias[n * 16 + lo];
#pragma unroll
        for (int r = 0; r < 4; ++r)
          outp[(size_t)(c * 16 + 4 * g + r) * OUTC + n * 16 + lo] =
              o[c][n][r] * lir[r] + bu;
      }
    }
  }
}

// ---------------------------------------------------------------------------
extern "C" void kernel_launch(void* const* d_in, const int* in_sizes, int n_in,
                              void* d_out, int out_size, void* d_ws, size_t ws_size,
                              hipStream_t stream) {
  (void)in_sizes; (void)n_in; (void)out_size; (void)ws_size;
  const float* x      = (const float*)d_in[0];
  const float* weight = (const float*)d_in[1];
  const float* bias   = (const float*)d_in[2];
  const float* wq     = (const float*)d_in[3];
  const float* bq     = (const float*)d_in[4];
  const float* wk     = (const float*)d_in[5];
  const float* bk     = (const float*)d_in[6];
  const float* wv     = (const float*)d_in[7];
  const float* bv     = (const float*)d_in[8];
  float* out = (float*)d_out;

  char* ws = (char*)d_ws;
  short* kbuf = (short*)(ws);                                   // 1 MiB [p][32]
  short* vfb  = (short*)(ws + ((size_t)1 << 20));               // 4 MiB VF tiles
  short* qlb  = (short*)(ws + ((size_t)5 << 20));               // 1 MiB QL tiles
  short* wqb  = (short*)(ws + ((size_t)6 << 20));               // 8 KiB
  short* wkb  = (short*)(ws + ((size_t)6 << 20) + 8192);        // 8 KiB
  short* wfT  = (short*)(ws + ((size_t)6 << 20) + 16384);       // 32 KiB
  float* bfu  = (float*)(ws + ((size_t)6 << 20) + 49152);       // 512 B

  hipLaunchKernelGGL(k_fuse, dim3(OUTC), dim3(CIN), 0, stream,
                     wq, wk, wv, weight, bv, wqb, wkb, wfT, bfu);
  hipLaunchKernelGGL(k_proj, dim3(NB * SEQ / 64), dim3(256), 0, stream,
                     x, bq, bk, wqb, wkb, wfT, bfu, qlb, kbuf, vfb);
  hipLaunchKernelGGL(k_attn, dim3(NB * SEQ / 64), dim3(512), 0, stream,
                     qlb, kbuf, vfb, bias, out);
}

// Round 14
// 53.060 us; speedup vs baseline: 1.3588x; 1.1057x over previous
//
#include <hip/hip_runtime.h>

#define NB   4
#define SEQ  4096
#define CIN  128
#define C4D  32
#define OUTC 128
#define LOG2E 1.44269504f

typedef __attribute__((ext_vector_type(8))) short bf16x8;
typedef __attribute__((ext_vector_type(4))) float f32x4;

__device__ __forceinline__ short f2bf(float f) {
  union { float f; unsigned u; } v; v.f = f;
  unsigned r = v.u + 0x7FFFu + ((v.u >> 16) & 1u);
  return (short)(r >> 16);
}

__device__ __forceinline__ unsigned cvt_pk_bf16(float lo, float hi) {
  unsigned r;
  asm("v_cvt_pk_bf16_f32 %0, %1, %2" : "=v"(r) : "v"(lo), "v"(hi));
  return r;
}

// native 2^x (v_exp_f32) — exp2f() without fast-math lowers to slow OCML.
__device__ __forceinline__ float fast_exp2(float x) {
  float r;
  asm("v_exp_f32 %0, %1" : "=v"(r) : "v"(x));
  return r;
}

__device__ __forceinline__ f32x4 mfma16(bf16x8 a, bf16x8 b, f32x4 c) {
  return __builtin_amdgcn_mfma_f32_16x16x32_bf16(a, b, c, 0, 0, 0);
}

// async 16B/lane global->LDS: per-lane global src, wave-uniform LDS base.
__device__ __forceinline__ void gload_lds16(const short* g, short* l) {
  __builtin_amdgcn_global_load_lds(
      (const __attribute__((address_space(1))) void*)(g),
      (__attribute__((address_space(3))) void*)(l), 16, 0, 0);
}

// ---------------------------------------------------------------------------
// Kernel 1: fold value-path weights. 4-way partial sums break the serial
// FMA chain.
// ---------------------------------------------------------------------------
__global__ void k_fuse(const float* __restrict__ wq, const float* __restrict__ wk,
                       const float* __restrict__ wv, const float* __restrict__ weight,
                       const float* __restrict__ bv,
                       short* __restrict__ wqb, short* __restrict__ wkb,
                       short* __restrict__ wfT, float* __restrict__ bfu) {
  int u = blockIdx.x, c = threadIdx.x;
  float a0 = 0.f, a1 = 0.f, a2 = 0.f, a3 = 0.f;
  for (int o = 0; o < OUTC; o += 4) {
    a0 += wv[(o + 0) * CIN + c] * weight[(o + 0) * OUTC + u];
    a1 += wv[(o + 1) * CIN + c] * weight[(o + 1) * OUTC + u];
    a2 += wv[(o + 2) * CIN + c] * weight[(o + 2) * OUTC + u];
    a3 += wv[(o + 3) * CIN + c] * weight[(o + 3) * OUTC + u];
  }
  wfT[u * CIN + c] = f2bf((a0 + a1) + (a2 + a3));
  if (u < C4D) {
    wqb[u * CIN + c] = f2bf(wq[u * CIN + c]);
    wkb[u * CIN + c] = f2bf(wk[u * CIN + c]);
  }
  if (c == 0) {
    float b0 = 0.f, b1 = 0.f;
    for (int o = 0; o < OUTC; o += 2) {
      b0 += bv[o] * weight[o * OUTC + u];
      b1 += bv[o + 1] * weight[(o + 1) * OUTC + u];
    }
    bfu[u] = b0 + b1;
  }
}

// ---------------------------------------------------------------------------
// Kernel 2: projections. Weights (wqb|wkb|wfT = contiguous 48KB in ws) are
// staged once into LDS with a T2-style XOR swizzle (fragment reads are
// stride-256B rows -> 16-way bank conflict unswizzled). All fragment reads
// become conflict-free(2-way) ds_read_b128. K pre-scaled by log2(e).
// ---------------------------------------------------------------------------
__device__ __forceinline__ int wswz(int byte) {
  return byte ^ (((byte >> 8) & 7) << 4);
}

__global__ __launch_bounds__(256) void k_proj(
    const float* __restrict__ x, const float* __restrict__ bq, const float* __restrict__ bk,
    const short* __restrict__ wall, const float* __restrict__ bfu,
    short* __restrict__ ql, short* __restrict__ kb, short* __restrict__ vfb) {
  const int tid = threadIdx.x;
  const int wid = tid >> 6, lane = tid & 63;
  const int lo = lane & 15, g = lane >> 4;
  const int p0 = blockIdx.x * 64 + wid * 16;

  __shared__ __align__(16) short WL[24576];   // 48KB swizzled weights
#pragma unroll
  for (int i = 0; i < 12; ++i) {
    bf16x8 v = *(const bf16x8*)(wall + i * 2048 + tid * 8);
    *(bf16x8*)((char*)WL + wswz((i * 2048 + tid * 8) * 2)) = v;
  }
  __syncthreads();

  auto wfrag = [&](int idx) -> bf16x8 {       // idx in shorts, abs within WL
    return *(const bf16x8*)((char*)WL + wswz(idx * 2));
  };

  f32x4 aq[2] = {}, ak[2] = {}, as_[8] = {};

#pragma unroll
  for (int kk = 0; kk < 4; ++kk) {
    const float* xp = x + (size_t)(p0 + lo) * CIN + kk * 32 + g * 8;
    float4 xa = *(const float4*)xp;
    float4 xb = *(const float4*)(xp + 4);
    bf16x8 af;
    af[0] = f2bf(xa.x); af[1] = f2bf(xa.y); af[2] = f2bf(xa.z); af[3] = f2bf(xa.w);
    af[4] = f2bf(xb.x); af[5] = f2bf(xb.y); af[6] = f2bf(xb.z); af[7] = f2bf(xb.w);
#pragma unroll
    for (int n = 0; n < 2; ++n) {
      bf16x8 bq_ = wfrag((n * 16 + lo) * CIN + kk * 32 + g * 8);
      aq[n] = mfma16(af, bq_, aq[n]);
      bf16x8 bk_ = wfrag(4096 + (n * 16 + lo) * CIN + kk * 32 + g * 8);
      ak[n] = mfma16(af, bk_, ak[n]);
    }
#pragma unroll
    for (int n = 0; n < 8; ++n) {
      bf16x8 bs = wfrag(8192 + (n * 16 + lo) * CIN + kk * 32 + g * 8);
      as_[n] = mfma16(af, bs, as_[n]);
    }
  }

#pragma unroll
  for (int n = 0; n < 2; ++n) {
    float bqv = bq[n * 16 + lo], bkv = bk[n * 16 + lo];
    int u = n * 16 + lo;
#pragma unroll
    for (int r = 0; r < 4; ++r) {
      int p = p0 + 4 * g + r;
      int bb = p >> 12, s = p & (SEQ - 1);
      ql[(size_t)bb * (SEQ * 32) + (size_t)(s >> 5) * 1024 + ((s >> 4) & 1) * 512 +
         (u >> 3) * 128 + (s & 15) * 8 + (u & 7)] = f2bf(aq[n][r] + bqv);
      kb[(size_t)p * C4D + u] = f2bf((ak[n][r] + bkv) * LOG2E);
    }
  }
  {
    const int p = p0 + 4 * g;          // r = 0; r=0..3 contiguous in VF
    const int bb = p >> 12, s = p & (SEQ - 1);
#pragma unroll
    for (int n = 0; n < 8; ++n) {
      int u = n * 16 + lo;
      float bvv = bfu[u];
      uint2 w;
      w.x = cvt_pk_bf16(as_[n][0] + bvv, as_[n][1] + bvv);
      w.y = cvt_pk_bf16(as_[n][2] + bvv, as_[n][3] + bvv);
      *(uint2*)&vfb[(size_t)bb * (SEQ * 128) + (size_t)(s >> 5) * 4096 + (u >> 4) * 512 +
                    ((s >> 2) & 3) * 128 + (u & 15) * 8 + ((s >> 4) & 1) * 4] = w;
    }
  }
}

// ---------------------------------------------------------------------------
// Kernel 3 (Design II + LDS-staged V + setprio): unchanged from R12 except
// s_setprio(1) around the QK and PV MFMA clusters (T5; independent-wave
// attn is the m191 +4-7% case).
// ---------------------------------------------------------------------------
__global__ __launch_bounds__(512, 2) void k_attn(
    const short* __restrict__ ql, const short* __restrict__ kb,
    const short* __restrict__ vfb, const float* __restrict__ bias,
    float* __restrict__ out) {
  const int tid = threadIdx.x;
  const int wid = tid >> 6, lane = tid & 63;
  const int lo = lane & 15, g = lane >> 4;
  const int bid = blockIdx.x;
  const int xb = ((bid & 7) << 5) | (bid >> 3);   // 256 blocks, bijective
  const int b = xb >> 6;
  const int iw = (xb & 63) * 64;

  __shared__ __align__(16) char smem[133120];
  short* Vs = (short*)smem;          // staging: 8 waves x 2 bufs x 4096 shorts
  float* LDSF = (float*)smem;        // merge overlay (after barrier)

  const short* qB = ql + (size_t)b * (SEQ * 32) + (size_t)wid * 16384;
  const short* vB = vfb + (size_t)b * (SEQ * 128) + (size_t)wid * 65536;
  short* Vw = Vs + wid * 8192;       // this wave's staging region

  bf16x8 kf[4];
#pragma unroll
  for (int c = 0; c < 4; ++c)
    kf[c] = *(const bf16x8*)(kb + (size_t)(b * SEQ + iw + 16 * c + lo) * C4D + g * 8);

  f32x4 o[4][8];
#pragma unroll
  for (int c = 0; c < 4; ++c)
#pragma unroll
    for (int n = 0; n < 8; ++n) o[c][n] = (f32x4){0.f, 0.f, 0.f, 0.f};

  float ma[4] = {-3e38f, -3e38f, -3e38f, -3e38f};
  float la[4] = {0.f, 0.f, 0.f, 0.f};
  const f32x4 zf = {0.f, 0.f, 0.f, 0.f};

  bf16x8 pf[4];

  // prologue: Q tile 0 first, then stage V tile 0 (QK_0 waits vmcnt(8)).
  bf16x8 qf0 = *(const bf16x8*)(qB + lane * 8);
  bf16x8 qf1 = *(const bf16x8*)(qB + 512 + lane * 8);
#pragma unroll
  for (int n = 0; n < 8; ++n)
    gload_lds16(vB + n * 512 + lane * 8, Vw + n * 512);

#pragma unroll 2
  for (int t = 0; t < 16; ++t) {
    const int cur = t & 1, nxt = cur ^ 1;

    // QK (waits only on qf regs: vmcnt(8) -> V_t staging still in flight)
    f32x4 s0[4], s1[4];
    float tm[4];
    __builtin_amdgcn_s_setprio(1);
#pragma unroll
    for (int c = 0; c < 4; ++c) {
      s0[c] = mfma16(qf0, kf[c], zf);
      s1[c] = mfma16(qf1, kf[c], zf);
    }
    __builtin_amdgcn_s_setprio(0);
#pragma unroll
    for (int c = 0; c < 4; ++c) {
      tm[c] = fmaxf(fmaxf(fmaxf(s0[c][0], s0[c][1]), fmaxf(s0[c][2], s0[c][3])),
                    fmaxf(fmaxf(s1[c][0], s1[c][1]), fmaxf(s1[c][2], s1[c][3])));
    }

    // prefetch t+1: Q FIRST (so future QK waits vmcnt(8), not 0), V after.
    if (t + 1 < 16) {
      const short* qt = qB + (size_t)(t + 1) * 1024;
      qf0 = *(const bf16x8*)(qt + lane * 8);
      qf1 = *(const bf16x8*)(qt + 512 + lane * 8);
      const short* vn = vB + (size_t)(t + 1) * 4096;
      short* vd = Vw + nxt * 4096;
#pragma unroll
      for (int n = 0; n < 8; ++n)
        gload_lds16(vn + n * 512 + lane * 8, vd + n * 512);
    }

    bool need = (tm[0] > ma[0] + 11.5f) | (tm[1] > ma[1] + 11.5f) |
                (tm[2] > ma[2] + 11.5f) | (tm[3] > ma[3] + 11.5f);
    if (__any(need)) {
#pragma unroll
      for (int c = 0; c < 4; ++c) {
        float rowm = fmaxf(tm[c], __shfl_xor(tm[c], 16, 64));
        rowm = fmaxf(rowm, __shfl_xor(rowm, 32, 64));
        float mnew = fmaxf(ma[c], rowm);
        float scale = fast_exp2(ma[c] - mnew);
        la[c] *= scale;
        float sc[4];
#pragma unroll
        for (int r = 0; r < 4; ++r) sc[r] = __shfl(scale, 4 * g + r, 64);
#pragma unroll
        for (int n = 0; n < 8; ++n)
#pragma unroll
          for (int r = 0; r < 4; ++r) o[c][n][r] *= sc[r];
        ma[c] = mnew;
      }
    }

#pragma unroll
    for (int c = 0; c < 4; ++c) {
      float p[8];
#pragma unroll
      for (int r = 0; r < 4; ++r) {
        p[r]     = fast_exp2(s0[c][r] - ma[c]);
        p[4 + r] = fast_exp2(s1[c][r] - ma[c]);
      }
      la[c] += (p[0] + p[1]) + (p[2] + p[3]) + ((p[4] + p[5]) + (p[6] + p[7]));
      union { bf16x8 v8; unsigned u[4]; } pk;
      pk.u[0] = cvt_pk_bf16(p[0], p[1]);
      pk.u[1] = cvt_pk_bf16(p[2], p[3]);
      pk.u[2] = cvt_pk_bf16(p[4], p[5]);
      pk.u[3] = cvt_pk_bf16(p[6], p[7]);
      pf[c] = pk.v8;
    }

    // V_t landed when <=10 newest VMEM ops (2 Q_{t+1} + 8 V_{t+1}) remain.
    asm volatile("s_waitcnt vmcnt(10)" ::: "memory");

    const short* vt = Vw + cur * 4096;
    __builtin_amdgcn_s_setprio(1);
#pragma unroll
    for (int n = 0; n < 8; ++n) {
      bf16x8 vfr = *(const bf16x8*)(vt + n * 512 + lane * 8);
      o[0][n] = mfma16(pf[0], vfr, o[0][n]);
      o[1][n] = mfma16(pf[1], vfr, o[1][n]);
      o[2][n] = mfma16(pf[2], vfr, o[2][n]);
      o[3][n] = mfma16(pf[3], vfr, o[3][n]);
    }
    __builtin_amdgcn_s_setprio(0);
  }

  // deferred l-reduce over g (each g covered distinct j)
#pragma unroll
  for (int c = 0; c < 4; ++c) {
    la[c] += __shfl_xor(la[c], 16, 64);
    la[c] += __shfl_xor(la[c], 32, 64);
  }

  __syncthreads();   // staging region dead; safe to overlay merge arrays

  auto write_slot = [&](int s) {
    float* OSs = LDSF + s * 8192;
#pragma unroll
    for (int c = 0; c < 4; ++c)
#pragma unroll
      for (int n = 0; n < 8; ++n)
        *(f32x4*)&OSs[(c * 8 + n) * 256 + lane * 4] = o[c][n];
    if (lane < 16) {
#pragma unroll
      for (int c = 0; c < 4; ++c) {
        LDSF[32768 + s * 64 + c * 16 + lo] = ma[c];
        LDSF[33024 + s * 64 + c * 16 + lo] = la[c];
      }
    }
  };
  auto merge_slot = [&](int s) {
    float* OSs = LDSF + s * 8192;
#pragma unroll
    for (int c = 0; c < 4; ++c) {
      float ms = LDSF[32768 + s * 64 + c * 16 + lo];
      float ls = LDSF[33024 + s * 64 + c * 16 + lo];
      float M = fmaxf(ma[c], ms);
      float eo = fast_exp2(ma[c] - M), es = fast_exp2(ms - M);
      la[c] = eo * la[c] + es * ls;
      ma[c] = M;
      float eor[4], esr[4];
#pragma unroll
      for (int r = 0; r < 4; ++r) {
        eor[r] = __shfl(eo, 4 * g + r, 64);
        esr[r] = __shfl(es, 4 * g + r, 64);
      }
#pragma unroll
      for (int n = 0; n < 8; ++n) {
        f32x4 v = *(f32x4*)&OSs[(c * 8 + n) * 256 + lane * 4];
#pragma unroll
        for (int r = 0; r < 4; ++r)
          o[c][n][r] = eor[r] * o[c][n][r] + esr[r] * v[r];
      }
    }
  };

  if (wid >= 4) write_slot(wid - 4);
  __syncthreads();
  if (wid < 4) merge_slot(wid);
  __syncthreads();
  if (wid == 1) write_slot(0);
  if (wid == 3) write_slot(1);
  __syncthreads();
  if (wid == 0) merge_slot(0);
  if (wid == 2) merge_slot(1);
  __syncthreads();
  if (wid == 2) write_slot(0);
  __syncthreads();
  if (wid == 0) {
    merge_slot(0);
    float* outp = out + (size_t)(b * SEQ + iw) * OUTC;
#pragma unroll
    for (int c = 0; c < 4; ++c) {
      float ia = 1.f / la[c];
      float lir[4];
#pragma unroll
      for (int r = 0; r < 4; ++r) lir[r] = __shfl(ia, 4 * g + r, 64);
#pragma unroll
      for (int n = 0; n < 8; ++n) {
        float bu = bias[n * 16 + lo];
#pragma unroll
        for (int r = 0; r < 4; ++r)
          outp[(size_t)(c * 16 + 4 * g + r) * OUTC + n * 16 + lo] =
              o[c][n][r] * lir[r] + bu;
      }
    }
  }
}

// ---------------------------------------------------------------------------
extern "C" void kernel_launch(void* const* d_in, const int* in_sizes, int n_in,
                              void* d_out, int out_size, void* d_ws, size_t ws_size,
                              hipStream_t stream) {
  (void)in_sizes; (void)n_in; (void)out_size; (void)ws_size;
  const float* x      = (const float*)d_in[0];
  const float* weight = (const float*)d_in[1];
  const float* bias   = (const float*)d_in[2];
  const float* wq     = (const float*)d_in[3];
  const float* bq     = (const float*)d_in[4];
  const float* wk     = (const float*)d_in[5];
  const float* bk     = (const float*)d_in[6];
  const float* wv     = (const float*)d_in[7];
  const float* bv     = (const float*)d_in[8];
  float* out = (float*)d_out;

  char* ws = (char*)d_ws;
  short* kbuf = (short*)(ws);                                   // 1 MiB [p][32]
  short* vfb  = (short*)(ws + ((size_t)1 << 20));               // 4 MiB VF tiles
  short* qlb  = (short*)(ws + ((size_t)5 << 20));               // 1 MiB QL tiles
  // wqb|wkb|wfT form one contiguous 48KB "wall" used by k_proj
  short* wqb  = (short*)(ws + ((size_t)6 << 20));               // 8 KiB
  short* wkb  = (short*)(ws + ((size_t)6 << 20) + 8192);        // 8 KiB
  short* wfT  = (short*)(ws + ((size_t)6 << 20) + 16384);       // 32 KiB
  float* bfu  = (float*)(ws + ((size_t)6 << 20) + 49152);       // 512 B

  hipLaunchKernelGGL(k_fuse, dim3(OUTC), dim3(CIN), 0, stream,
                     wq, wk, wv, weight, bv, wqb, wkb, wfT, bfu);
  hipLaunchKernelGGL(k_proj, dim3(NB * SEQ / 64), dim3(256), 0, stream,
                     x, bq, bk, wqb /* = wall */, bfu, qlb, kbuf, vfb);
  hipLaunchKernelGGL(k_attn, dim3(NB * SEQ / 64), dim3(512), 0, stream,
                     qlb, kbuf, vfb, bias, out);
}

// Round 15
// 50.299 us; speedup vs baseline: 1.4334x; 1.0549x over previous
//
#include <hip/hip_runtime.h>

#define NB   4
#define SEQ  4096
#define CIN  128
#define C4D  32
#define OUTC 128
#define LOG2E 1.44269504f

typedef __attribute__((ext_vector_type(8))) short bf16x8;
typedef __attribute__((ext_vector_type(4))) float f32x4;

__device__ __forceinline__ short f2bf(float f) {
  union { float f; unsigned u; } v; v.f = f;
  unsigned r = v.u + 0x7FFFu + ((v.u >> 16) & 1u);
  return (short)(r >> 16);
}

__device__ __forceinline__ unsigned cvt_pk_bf16(float lo, float hi) {
  unsigned r;
  asm("v_cvt_pk_bf16_f32 %0, %1, %2" : "=v"(r) : "v"(lo), "v"(hi));
  return r;
}

// native 2^x (v_exp_f32) — exp2f() without fast-math lowers to slow OCML.
__device__ __forceinline__ float fast_exp2(float x) {
  float r;
  asm("v_exp_f32 %0, %1" : "=v"(r) : "v"(x));
  return r;
}

__device__ __forceinline__ f32x4 mfma16(bf16x8 a, bf16x8 b, f32x4 c) {
  return __builtin_amdgcn_mfma_f32_16x16x32_bf16(a, b, c, 0, 0, 0);
}

// ---------------------------------------------------------------------------
// Kernel 1: fold value-path weights (unchanged from R14).
// ---------------------------------------------------------------------------
__global__ void k_fuse(const float* __restrict__ wq, const float* __restrict__ wk,
                       const float* __restrict__ wv, const float* __restrict__ weight,
                       const float* __restrict__ bv,
                       short* __restrict__ wqb, short* __restrict__ wkb,
                       short* __restrict__ wfT, float* __restrict__ bfu) {
  int u = blockIdx.x, c = threadIdx.x;
  float a0 = 0.f, a1 = 0.f, a2 = 0.f, a3 = 0.f;
  for (int o = 0; o < OUTC; o += 4) {
    a0 += wv[(o + 0) * CIN + c] * weight[(o + 0) * OUTC + u];
    a1 += wv[(o + 1) * CIN + c] * weight[(o + 1) * OUTC + u];
    a2 += wv[(o + 2) * CIN + c] * weight[(o + 2) * OUTC + u];
    a3 += wv[(o + 3) * CIN + c] * weight[(o + 3) * OUTC + u];
  }
  wfT[u * CIN + c] = f2bf((a0 + a1) + (a2 + a3));
  if (u < C4D) {
    wqb[u * CIN + c] = f2bf(wq[u * CIN + c]);
    wkb[u * CIN + c] = f2bf(wk[u * CIN + c]);
  }
  if (c == 0) {
    float b0 = 0.f, b1 = 0.f;
    for (int o = 0; o < OUTC; o += 2) {
      b0 += bv[o] * weight[o * OUTC + u];
      b1 += bv[o + 1] * weight[(o + 1) * OUTC + u];
    }
    bfu[u] = b0 + b1;
  }
}

// ---------------------------------------------------------------------------
// Kernel 2: projections (unchanged from R14). LDS-swizzled weights,
// K pre-scaled by log2(e), fragment-linear QL/VF outputs.
// ---------------------------------------------------------------------------
__device__ __forceinline__ int wswz(int byte) {
  return byte ^ (((byte >> 8) & 7) << 4);
}

__global__ __launch_bounds__(256) void k_proj(
    const float* __restrict__ x, const float* __restrict__ bq, const float* __restrict__ bk,
    const short* __restrict__ wall, const float* __restrict__ bfu,
    short* __restrict__ ql, short* __restrict__ kb, short* __restrict__ vfb) {
  const int tid = threadIdx.x;
  const int wid = tid >> 6, lane = tid & 63;
  const int lo = lane & 15, g = lane >> 4;
  const int p0 = blockIdx.x * 64 + wid * 16;

  __shared__ __align__(16) short WL[24576];   // 48KB swizzled weights
#pragma unroll
  for (int i = 0; i < 12; ++i) {
    bf16x8 v = *(const bf16x8*)(wall + i * 2048 + tid * 8);
    *(bf16x8*)((char*)WL + wswz((i * 2048 + tid * 8) * 2)) = v;
  }
  __syncthreads();

  auto wfrag = [&](int idx) -> bf16x8 {
    return *(const bf16x8*)((char*)WL + wswz(idx * 2));
  };

  f32x4 aq[2] = {}, ak[2] = {}, as_[8] = {};

#pragma unroll
  for (int kk = 0; kk < 4; ++kk) {
    const float* xp = x + (size_t)(p0 + lo) * CIN + kk * 32 + g * 8;
    float4 xa = *(const float4*)xp;
    float4 xb = *(const float4*)(xp + 4);
    bf16x8 af;
    af[0] = f2bf(xa.x); af[1] = f2bf(xa.y); af[2] = f2bf(xa.z); af[3] = f2bf(xa.w);
    af[4] = f2bf(xb.x); af[5] = f2bf(xb.y); af[6] = f2bf(xb.z); af[7] = f2bf(xb.w);
#pragma unroll
    for (int n = 0; n < 2; ++n) {
      bf16x8 bq_ = wfrag((n * 16 + lo) * CIN + kk * 32 + g * 8);
      aq[n] = mfma16(af, bq_, aq[n]);
      bf16x8 bk_ = wfrag(4096 + (n * 16 + lo) * CIN + kk * 32 + g * 8);
      ak[n] = mfma16(af, bk_, ak[n]);
    }
#pragma unroll
    for (int n = 0; n < 8; ++n) {
      bf16x8 bs = wfrag(8192 + (n * 16 + lo) * CIN + kk * 32 + g * 8);
      as_[n] = mfma16(af, bs, as_[n]);
    }
  }

#pragma unroll
  for (int n = 0; n < 2; ++n) {
    float bqv = bq[n * 16 + lo], bkv = bk[n * 16 + lo];
    int u = n * 16 + lo;
#pragma unroll
    for (int r = 0; r < 4; ++r) {
      int p = p0 + 4 * g + r;
      int bb = p >> 12, s = p & (SEQ - 1);
      ql[(size_t)bb * (SEQ * 32) + (size_t)(s >> 5) * 1024 + ((s >> 4) & 1) * 512 +
         (u >> 3) * 128 + (s & 15) * 8 + (u & 7)] = f2bf(aq[n][r] + bqv);
      kb[(size_t)p * C4D + u] = f2bf((ak[n][r] + bkv) * LOG2E);
    }
  }
  {
    const int p = p0 + 4 * g;          // r = 0; r=0..3 contiguous in VF
    const int bb = p >> 12, s = p & (SEQ - 1);
#pragma unroll
    for (int n = 0; n < 8; ++n) {
      int u = n * 16 + lo;
      float bvv = bfu[u];
      uint2 w;
      w.x = cvt_pk_bf16(as_[n][0] + bvv, as_[n][1] + bvv);
      w.y = cvt_pk_bf16(as_[n][2] + bvv, as_[n][3] + bvv);
      *(uint2*)&vfb[(size_t)bb * (SEQ * 128) + (size_t)(s >> 5) * 4096 + (u >> 4) * 512 +
                    ((s >> 2) & 3) * 128 + (u & 15) * 8 + ((s >> 4) & 1) * 4] = w;
    }
  }
}

// ---------------------------------------------------------------------------
// Kernel 3 (Design III): wave = 32 i-rows (kf[2], o[2][8]=64 acc regs),
// block = 4 waves / 256 thr on the same 32 rows, j-split 4 (1024 j each,
// 32 iters of 32-j). Direct-global V into regs (XCD-L2-resident; issue V
// first, QK waits vmcnt(10), PV waits vmcnt(2)). 3 waves/SIMD occupancy.
// Defer-max softmax (native v_exp), deferred l-reduce, cvt_pk, setprio.
// 2-round LDS tree merge (33.5 KB).
// ---------------------------------------------------------------------------
__global__ __launch_bounds__(256, 3) void k_attn(
    const short* __restrict__ ql, const short* __restrict__ kb,
    const short* __restrict__ vfb, const float* __restrict__ bias,
    float* __restrict__ out) {
  const int tid = threadIdx.x;
  const int wid = tid >> 6, lane = tid & 63;
  const int lo = lane & 15, g = lane >> 4;
  const int bid = blockIdx.x;
  const int xb = ((bid & 7) << 6) | (bid >> 3);   // 512 blocks, bijective
  const int b = xb >> 7;
  const int iw = (xb & 127) * 32;

  __shared__ float OS[2][4096];
  __shared__ float MS[2][32], LS[2][32];

  const short* qB = ql + (size_t)b * (SEQ * 32) + (size_t)wid * 32768;
  const short* vB = vfb + (size_t)b * (SEQ * 128) + (size_t)wid * 131072;

  bf16x8 kf[2];
#pragma unroll
  for (int c = 0; c < 2; ++c)
    kf[c] = *(const bf16x8*)(kb + (size_t)(b * SEQ + iw + 16 * c + lo) * C4D + g * 8);

  f32x4 o[2][8];
#pragma unroll
  for (int c = 0; c < 2; ++c)
#pragma unroll
    for (int n = 0; n < 8; ++n) o[c][n] = (f32x4){0.f, 0.f, 0.f, 0.f};

  float ma[2] = {-3e38f, -3e38f};
  float la[2] = {0.f, 0.f};
  const f32x4 zf = {0.f, 0.f, 0.f, 0.f};

  bf16x8 pf[2];

  // prologue: Q tile 0
  bf16x8 qf0 = *(const bf16x8*)(qB + lane * 8);
  bf16x8 qf1 = *(const bf16x8*)(qB + 512 + lane * 8);

  for (int t = 0; t < 32; ++t) {
    // V_t issued first: its latency hides under QK + softmax.
    bf16x8 vfr[8];
    const short* vt = vB + (size_t)t * 4096;
#pragma unroll
    for (int n = 0; n < 8; ++n)
      vfr[n] = *(const bf16x8*)(vt + n * 512 + lane * 8);

    f32x4 s0[2], s1[2];
    float tm[2];
    __builtin_amdgcn_s_setprio(1);
#pragma unroll
    for (int c = 0; c < 2; ++c) {
      s0[c] = mfma16(qf0, kf[c], zf);
      s1[c] = mfma16(qf1, kf[c], zf);
    }
    __builtin_amdgcn_s_setprio(0);
#pragma unroll
    for (int c = 0; c < 2; ++c) {
      tm[c] = fmaxf(fmaxf(fmaxf(s0[c][0], s0[c][1]), fmaxf(s0[c][2], s0[c][3])),
                    fmaxf(fmaxf(s1[c][0], s1[c][1]), fmaxf(s1[c][2], s1[c][3])));
    }

    // Q prefetch for t+1 (issued after V_t, so PV_t waits only vmcnt(2))
    if (t + 1 < 32) {
      const short* qt = qB + (size_t)(t + 1) * 1024;
      qf0 = *(const bf16x8*)(qt + lane * 8);
      qf1 = *(const bf16x8*)(qt + 512 + lane * 8);
    }

    bool need = (tm[0] > ma[0] + 11.5f) | (tm[1] > ma[1] + 11.5f);
    if (__any(need)) {
#pragma unroll
      for (int c = 0; c < 2; ++c) {
        float rowm = fmaxf(tm[c], __shfl_xor(tm[c], 16, 64));
        rowm = fmaxf(rowm, __shfl_xor(rowm, 32, 64));
        float mnew = fmaxf(ma[c], rowm);
        float scale = fast_exp2(ma[c] - mnew);
        la[c] *= scale;
        float sc[4];
#pragma unroll
        for (int r = 0; r < 4; ++r) sc[r] = __shfl(scale, 4 * g + r, 64);
#pragma unroll
        for (int n = 0; n < 8; ++n)
#pragma unroll
          for (int r = 0; r < 4; ++r) o[c][n][r] *= sc[r];
        ma[c] = mnew;
      }
    }

#pragma unroll
    for (int c = 0; c < 2; ++c) {
      float p[8];
#pragma unroll
      for (int r = 0; r < 4; ++r) {
        p[r]     = fast_exp2(s0[c][r] - ma[c]);
        p[4 + r] = fast_exp2(s1[c][r] - ma[c]);
      }
      la[c] += (p[0] + p[1]) + (p[2] + p[3]) + ((p[4] + p[5]) + (p[6] + p[7]));
      union { bf16x8 v8; unsigned u[4]; } pk;
      pk.u[0] = cvt_pk_bf16(p[0], p[1]);
      pk.u[1] = cvt_pk_bf16(p[2], p[3]);
      pk.u[2] = cvt_pk_bf16(p[4], p[5]);
      pk.u[3] = cvt_pk_bf16(p[6], p[7]);
      pf[c] = pk.v8;
    }

    __builtin_amdgcn_s_setprio(1);
#pragma unroll
    for (int n = 0; n < 8; ++n) {
      o[0][n] = mfma16(pf[0], vfr[n], o[0][n]);
      o[1][n] = mfma16(pf[1], vfr[n], o[1][n]);
    }
    __builtin_amdgcn_s_setprio(0);
  }

  // deferred l-reduce over g (each g covered distinct j)
#pragma unroll
  for (int c = 0; c < 2; ++c) {
    la[c] += __shfl_xor(la[c], 16, 64);
    la[c] += __shfl_xor(la[c], 32, 64);
  }

  auto write_slot = [&](int s) {
#pragma unroll
    for (int c = 0; c < 2; ++c)
#pragma unroll
      for (int n = 0; n < 8; ++n)
        *(f32x4*)&OS[s][(c * 8 + n) * 256 + lane * 4] = o[c][n];
    if (lane < 16) {
#pragma unroll
      for (int c = 0; c < 2; ++c) {
        MS[s][c * 16 + lo] = ma[c];
        LS[s][c * 16 + lo] = la[c];
      }
    }
  };
  auto merge_slot = [&](int s) {
#pragma unroll
    for (int c = 0; c < 2; ++c) {
      float ms = MS[s][c * 16 + lo];
      float ls = LS[s][c * 16 + lo];
      float M = fmaxf(ma[c], ms);
      float eo = fast_exp2(ma[c] - M), es = fast_exp2(ms - M);
      la[c] = eo * la[c] + es * ls;
      ma[c] = M;
      float eor[4], esr[4];
#pragma unroll
      for (int r = 0; r < 4; ++r) {
        eor[r] = __shfl(eo, 4 * g + r, 64);
        esr[r] = __shfl(es, 4 * g + r, 64);
      }
#pragma unroll
      for (int n = 0; n < 8; ++n) {
        f32x4 v = *(f32x4*)&OS[s][(c * 8 + n) * 256 + lane * 4];
#pragma unroll
        for (int r = 0; r < 4; ++r)
          o[c][n][r] = eor[r] * o[c][n][r] + esr[r] * v[r];
      }
    }
  };

  if (wid == 1) write_slot(0);
  if (wid == 3) write_slot(1);
  __syncthreads();
  if (wid == 0) merge_slot(0);
  if (wid == 2) merge_slot(1);
  __syncthreads();
  if (wid == 2) write_slot(0);
  __syncthreads();
  if (wid == 0) {
    merge_slot(0);
    float* outp = out + (size_t)(b * SEQ + iw) * OUTC;
#pragma unroll
    for (int c = 0; c < 2; ++c) {
      float ia = 1.f / la[c];
      float lir[4];
#pragma unroll
      for (int r = 0; r < 4; ++r) lir[r] = __shfl(ia, 4 * g + r, 64);
#pragma unroll
      for (int n = 0; n < 8; ++n) {
        float bu = bias[n * 16 + lo];
#pragma unroll
        for (int r = 0; r < 4; ++r)
          outp[(size_t)(c * 16 + 4 * g + r) * OUTC + n * 16 + lo] =
              o[c][n][r] * lir[r] + bu;
      }
    }
  }
}

// ---------------------------------------------------------------------------
extern "C" void kernel_launch(void* const* d_in, const int* in_sizes, int n_in,
                              void* d_out, int out_size, void* d_ws, size_t ws_size,
                              hipStream_t stream) {
  (void)in_sizes; (void)n_in; (void)out_size; (void)ws_size;
  const float* x      = (const float*)d_in[0];
  const float* weight = (const float*)d_in[1];
  const float* bias   = (const float*)d_in[2];
  const float* wq     = (const float*)d_in[3];
  const float* bq     = (const float*)d_in[4];
  const float* wk     = (const float*)d_in[5];
  const float* bk     = (const float*)d_in[6];
  const float* wv     = (const float*)d_in[7];
  const float* bv     = (const float*)d_in[8];
  float* out = (float*)d_out;

  char* ws = (char*)d_ws;
  short* kbuf = (short*)(ws);                                   // 1 MiB [p][32]
  short* vfb  = (short*)(ws + ((size_t)1 << 20));               // 4 MiB VF tiles
  short* qlb  = (short*)(ws + ((size_t)5 << 20));               // 1 MiB QL tiles
  // wqb|wkb|wfT form one contiguous 48KB "wall" used by k_proj
  short* wqb  = (short*)(ws + ((size_t)6 << 20));               // 8 KiB
  short* wkb  = (short*)(ws + ((size_t)6 << 20) + 8192);        // 8 KiB
  short* wfT  = (short*)(ws + ((size_t)6 << 20) + 16384);       // 32 KiB
  float* bfu  = (float*)(ws + ((size_t)6 << 20) + 49152);       // 512 B

  hipLaunchKernelGGL(k_fuse, dim3(OUTC), dim3(CIN), 0, stream,
                     wq, wk, wv, weight, bv, wqb, wkb, wfT, bfu);
  hipLaunchKernelGGL(k_proj, dim3(NB * SEQ / 64), dim3(256), 0, stream,
                     x, bq, bk, wqb /* = wall */, bfu, qlb, kbuf, vfb);
  hipLaunchKernelGGL(k_attn, dim3(NB * SEQ / 32), dim3(256), 0, stream,
                     qlb, kbuf, vfb, bias, out);
}

// Round 16
// 49.328 us; speedup vs baseline: 1.4616x; 1.0197x over previous
//
#include <hip/hip_runtime.h>

#define NB   4
#define SEQ  4096
#define CIN  128
#define C4D  32
#define OUTC 128
#define LOG2E 1.44269504f

typedef __attribute__((ext_vector_type(8))) short bf16x8;
typedef __attribute__((ext_vector_type(4))) float f32x4;

__device__ __forceinline__ short f2bf(float f) {
  union { float f; unsigned u; } v; v.f = f;
  unsigned r = v.u + 0x7FFFu + ((v.u >> 16) & 1u);
  return (short)(r >> 16);
}

__device__ __forceinline__ unsigned cvt_pk_bf16(float lo, float hi) {
  unsigned r;
  asm("v_cvt_pk_bf16_f32 %0, %1, %2" : "=v"(r) : "v"(lo), "v"(hi));
  return r;
}

// native 2^x (v_exp_f32) — exp2f() without fast-math lowers to slow OCML.
__device__ __forceinline__ float fast_exp2(float x) {
  float r;
  asm("v_exp_f32 %0, %1" : "=v"(r) : "v"(x));
  return r;
}

__device__ __forceinline__ f32x4 mfma16(bf16x8 a, bf16x8 b, f32x4 c) {
  return __builtin_amdgcn_mfma_f32_16x16x32_bf16(a, b, c, 0, 0, 0);
}

// ---------------------------------------------------------------------------
// Kernel 1: fold value-path weights (unchanged).
// ---------------------------------------------------------------------------
__global__ void k_fuse(const float* __restrict__ wq, const float* __restrict__ wk,
                       const float* __restrict__ wv, const float* __restrict__ weight,
                       const float* __restrict__ bv,
                       short* __restrict__ wqb, short* __restrict__ wkb,
                       short* __restrict__ wfT, float* __restrict__ bfu) {
  int u = blockIdx.x, c = threadIdx.x;
  float a0 = 0.f, a1 = 0.f, a2 = 0.f, a3 = 0.f;
  for (int o = 0; o < OUTC; o += 4) {
    a0 += wv[(o + 0) * CIN + c] * weight[(o + 0) * OUTC + u];
    a1 += wv[(o + 1) * CIN + c] * weight[(o + 1) * OUTC + u];
    a2 += wv[(o + 2) * CIN + c] * weight[(o + 2) * OUTC + u];
    a3 += wv[(o + 3) * CIN + c] * weight[(o + 3) * OUTC + u];
  }
  wfT[u * CIN + c] = f2bf((a0 + a1) + (a2 + a3));
  if (u < C4D) {
    wqb[u * CIN + c] = f2bf(wq[u * CIN + c]);
    wkb[u * CIN + c] = f2bf(wk[u * CIN + c]);
  }
  if (c == 0) {
    float b0 = 0.f, b1 = 0.f;
    for (int o = 0; o < OUTC; o += 2) {
      b0 += bv[o] * weight[o * OUTC + u];
      b1 += bv[o + 1] * weight[(o + 1) * OUTC + u];
    }
    bfu[u] = b0 + b1;
  }
}

// ---------------------------------------------------------------------------
// Kernel 2: projections (unchanged). LDS-swizzled weights, K pre-scaled by
// log2(e), fragment-linear QL/VF outputs.
// ---------------------------------------------------------------------------
__device__ __forceinline__ int wswz(int byte) {
  return byte ^ (((byte >> 8) & 7) << 4);
}

__global__ __launch_bounds__(256) void k_proj(
    const float* __restrict__ x, const float* __restrict__ bq, const float* __restrict__ bk,
    const short* __restrict__ wall, const float* __restrict__ bfu,
    short* __restrict__ ql, short* __restrict__ kb, short* __restrict__ vfb) {
  const int tid = threadIdx.x;
  const int wid = tid >> 6, lane = tid & 63;
  const int lo = lane & 15, g = lane >> 4;
  const int p0 = blockIdx.x * 64 + wid * 16;

  __shared__ __align__(16) short WL[24576];   // 48KB swizzled weights
#pragma unroll
  for (int i = 0; i < 12; ++i) {
    bf16x8 v = *(const bf16x8*)(wall + i * 2048 + tid * 8);
    *(bf16x8*)((char*)WL + wswz((i * 2048 + tid * 8) * 2)) = v;
  }
  __syncthreads();

  auto wfrag = [&](int idx) -> bf16x8 {
    return *(const bf16x8*)((char*)WL + wswz(idx * 2));
  };

  f32x4 aq[2] = {}, ak[2] = {}, as_[8] = {};

#pragma unroll
  for (int kk = 0; kk < 4; ++kk) {
    const float* xp = x + (size_t)(p0 + lo) * CIN + kk * 32 + g * 8;
    float4 xa = *(const float4*)xp;
    float4 xb = *(const float4*)(xp + 4);
    bf16x8 af;
    af[0] = f2bf(xa.x); af[1] = f2bf(xa.y); af[2] = f2bf(xa.z); af[3] = f2bf(xa.w);
    af[4] = f2bf(xb.x); af[5] = f2bf(xb.y); af[6] = f2bf(xb.z); af[7] = f2bf(xb.w);
#pragma unroll
    for (int n = 0; n < 2; ++n) {
      bf16x8 bq_ = wfrag((n * 16 + lo) * CIN + kk * 32 + g * 8);
      aq[n] = mfma16(af, bq_, aq[n]);
      bf16x8 bk_ = wfrag(4096 + (n * 16 + lo) * CIN + kk * 32 + g * 8);
      ak[n] = mfma16(af, bk_, ak[n]);
    }
#pragma unroll
    for (int n = 0; n < 8; ++n) {
      bf16x8 bs = wfrag(8192 + (n * 16 + lo) * CIN + kk * 32 + g * 8);
      as_[n] = mfma16(af, bs, as_[n]);
    }
  }

#pragma unroll
  for (int n = 0; n < 2; ++n) {
    float bqv = bq[n * 16 + lo], bkv = bk[n * 16 + lo];
    int u = n * 16 + lo;
#pragma unroll
    for (int r = 0; r < 4; ++r) {
      int p = p0 + 4 * g + r;
      int bb = p >> 12, s = p & (SEQ - 1);
      ql[(size_t)bb * (SEQ * 32) + (size_t)(s >> 5) * 1024 + ((s >> 4) & 1) * 512 +
         (u >> 3) * 128 + (s & 15) * 8 + (u & 7)] = f2bf(aq[n][r] + bqv);
      kb[(size_t)p * C4D + u] = f2bf((ak[n][r] + bkv) * LOG2E);
    }
  }
  {
    const int p = p0 + 4 * g;          // r = 0; r=0..3 contiguous in VF
    const int bb = p >> 12, s = p & (SEQ - 1);
#pragma unroll
    for (int n = 0; n < 8; ++n) {
      int u = n * 16 + lo;
      float bvv = bfu[u];
      uint2 w;
      w.x = cvt_pk_bf16(as_[n][0] + bvv, as_[n][1] + bvv);
      w.y = cvt_pk_bf16(as_[n][2] + bvv, as_[n][3] + bvv);
      *(uint2*)&vfb[(size_t)bb * (SEQ * 128) + (size_t)(s >> 5) * 4096 + (u >> 4) * 512 +
                    ((s >> 2) & 3) * 128 + (u & 15) * 8 + ((s >> 4) & 1) * 4] = w;
    }
  }
}

// ---------------------------------------------------------------------------
// Kernel 3 (Design III, frozen-max + l-via-MFMA): wave = 32 i-rows, 4 waves
// per block, j-split 4, 32 iters. Tile 0 peeled: computes the exact per-row
// max once; main loop is BRANCH-FREE (no max tracking, no rescale — p
// bounded by 2^~13, safe in f32/bf16, merge exact for stale maxima).
// Row-sum l accumulated by an extra MFMA with a constant-ones B fragment
// (ol[c][r] = l for row 4g+r — epilogue needs no shuffles for 1/l).
// ---------------------------------------------------------------------------
__global__ __launch_bounds__(256, 3) void k_attn(
    const short* __restrict__ ql, const short* __restrict__ kb,
    const short* __restrict__ vfb, const float* __restrict__ bias,
    float* __restrict__ out) {
  const int tid = threadIdx.x;
  const int wid = tid >> 6, lane = tid & 63;
  const int lo = lane & 15, g = lane >> 4;
  const int bid = blockIdx.x;
  const int xb = ((bid & 7) << 6) | (bid >> 3);   // 512 blocks, bijective
  const int b = xb >> 7;
  const int iw = (xb & 127) * 32;

  __shared__ float OS[2][4096];
  __shared__ float OL[2][512];
  __shared__ float MS[2][32];

  const short* qB = ql + (size_t)b * (SEQ * 32) + (size_t)wid * 32768;
  const short* vB = vfb + (size_t)b * (SEQ * 128) + (size_t)wid * 131072;

  bf16x8 kf[2];
#pragma unroll
  for (int c = 0; c < 2; ++c)
    kf[c] = *(const bf16x8*)(kb + (size_t)(b * SEQ + iw + 16 * c + lo) * C4D + g * 8);

  f32x4 o[2][8];
#pragma unroll
  for (int c = 0; c < 2; ++c)
#pragma unroll
    for (int n = 0; n < 8; ++n) o[c][n] = (f32x4){0.f, 0.f, 0.f, 0.f};
  f32x4 olv[2];
  olv[0] = (f32x4){0.f, 0.f, 0.f, 0.f};
  olv[1] = (f32x4){0.f, 0.f, 0.f, 0.f};

  float ma[2];
  const f32x4 zf = {0.f, 0.f, 0.f, 0.f};
  bf16x8 ones;
#pragma unroll
  for (int e = 0; e < 8; ++e) ones[e] = (short)0x3F80;   // bf16 1.0

  bf16x8 pf[2];

  // prologue: Q tile 0
  bf16x8 qf0 = *(const bf16x8*)(qB + lane * 8);
  bf16x8 qf1 = *(const bf16x8*)(qB + 512 + lane * 8);

  // ---- tile 0 (peeled): exact per-row max, then process ----
  {
    bf16x8 vfr[8];
#pragma unroll
    for (int n = 0; n < 8; ++n)
      vfr[n] = *(const bf16x8*)(vB + n * 512 + lane * 8);

    f32x4 s0[2], s1[2];
    __builtin_amdgcn_s_setprio(1);
#pragma unroll
    for (int c = 0; c < 2; ++c) {
      s0[c] = mfma16(qf0, kf[c], zf);
      s1[c] = mfma16(qf1, kf[c], zf);
    }
    __builtin_amdgcn_s_setprio(0);

    // Q prefetch for t=1
    qf0 = *(const bf16x8*)(qB + 1024 + lane * 8);
    qf1 = *(const bf16x8*)(qB + 1536 + lane * 8);

#pragma unroll
    for (int c = 0; c < 2; ++c) {
      float tm = fmaxf(fmaxf(fmaxf(s0[c][0], s0[c][1]), fmaxf(s0[c][2], s0[c][3])),
                       fmaxf(fmaxf(s1[c][0], s1[c][1]), fmaxf(s1[c][2], s1[c][3])));
      tm = fmaxf(tm, __shfl_xor(tm, 16, 64));
      tm = fmaxf(tm, __shfl_xor(tm, 32, 64));
      ma[c] = tm;                       // frozen for the whole pass
    }

#pragma unroll
    for (int c = 0; c < 2; ++c) {
      float p[8];
#pragma unroll
      for (int r = 0; r < 4; ++r) {
        p[r]     = fast_exp2(s0[c][r] - ma[c]);
        p[4 + r] = fast_exp2(s1[c][r] - ma[c]);
      }
      union { bf16x8 v8; unsigned u[4]; } pk;
      pk.u[0] = cvt_pk_bf16(p[0], p[1]);
      pk.u[1] = cvt_pk_bf16(p[2], p[3]);
      pk.u[2] = cvt_pk_bf16(p[4], p[5]);
      pk.u[3] = cvt_pk_bf16(p[6], p[7]);
      pf[c] = pk.v8;
    }

    __builtin_amdgcn_s_setprio(1);
#pragma unroll
    for (int n = 0; n < 8; ++n) {
      o[0][n] = mfma16(pf[0], vfr[n], o[0][n]);
      o[1][n] = mfma16(pf[1], vfr[n], o[1][n]);
    }
    olv[0] = mfma16(pf[0], ones, olv[0]);
    olv[1] = mfma16(pf[1], ones, olv[1]);
    __builtin_amdgcn_s_setprio(0);
  }

  // ---- main loop: branch-free ----
  for (int t = 1; t < 32; ++t) {
    bf16x8 vfr[8];
    const short* vt = vB + (size_t)t * 4096;
#pragma unroll
    for (int n = 0; n < 8; ++n)
      vfr[n] = *(const bf16x8*)(vt + n * 512 + lane * 8);

    f32x4 s0[2], s1[2];
    __builtin_amdgcn_s_setprio(1);
#pragma unroll
    for (int c = 0; c < 2; ++c) {
      s0[c] = mfma16(qf0, kf[c], zf);
      s1[c] = mfma16(qf1, kf[c], zf);
    }
    __builtin_amdgcn_s_setprio(0);

    if (t + 1 < 32) {
      const short* qt = qB + (size_t)(t + 1) * 1024;
      qf0 = *(const bf16x8*)(qt + lane * 8);
      qf1 = *(const bf16x8*)(qt + 512 + lane * 8);
    }

#pragma unroll
    for (int c = 0; c < 2; ++c) {
      float p[8];
#pragma unroll
      for (int r = 0; r < 4; ++r) {
        p[r]     = fast_exp2(s0[c][r] - ma[c]);
        p[4 + r] = fast_exp2(s1[c][r] - ma[c]);
      }
      union { bf16x8 v8; unsigned u[4]; } pk;
      pk.u[0] = cvt_pk_bf16(p[0], p[1]);
      pk.u[1] = cvt_pk_bf16(p[2], p[3]);
      pk.u[2] = cvt_pk_bf16(p[4], p[5]);
      pk.u[3] = cvt_pk_bf16(p[6], p[7]);
      pf[c] = pk.v8;
    }

    __builtin_amdgcn_s_setprio(1);
#pragma unroll
    for (int n = 0; n < 8; ++n) {
      o[0][n] = mfma16(pf[0], vfr[n], o[0][n]);
      o[1][n] = mfma16(pf[1], vfr[n], o[1][n]);
    }
    olv[0] = mfma16(pf[0], ones, olv[0]);
    olv[1] = mfma16(pf[1], ones, olv[1]);
    __builtin_amdgcn_s_setprio(0);
  }

  auto write_slot = [&](int s) {
#pragma unroll
    for (int c = 0; c < 2; ++c)
#pragma unroll
      for (int n = 0; n < 8; ++n)
        *(f32x4*)&OS[s][(c * 8 + n) * 256 + lane * 4] = o[c][n];
#pragma unroll
    for (int c = 0; c < 2; ++c)
      *(f32x4*)&OL[s][c * 256 + lane * 4] = olv[c];
    if (lane < 16) {
#pragma unroll
      for (int c = 0; c < 2; ++c) MS[s][c * 16 + lo] = ma[c];
    }
  };
  auto merge_slot = [&](int s) {
#pragma unroll
    for (int c = 0; c < 2; ++c) {
      float ms = MS[s][c * 16 + lo];
      float M = fmaxf(ma[c], ms);
      float eo = fast_exp2(ma[c] - M), es = fast_exp2(ms - M);
      ma[c] = M;
      float eor[4], esr[4];
#pragma unroll
      for (int r = 0; r < 4; ++r) {
        eor[r] = __shfl(eo, 4 * g + r, 64);
        esr[r] = __shfl(es, 4 * g + r, 64);
      }
#pragma unroll
      for (int n = 0; n < 8; ++n) {
        f32x4 v = *(f32x4*)&OS[s][(c * 8 + n) * 256 + lane * 4];
#pragma unroll
        for (int r = 0; r < 4; ++r)
          o[c][n][r] = eor[r] * o[c][n][r] + esr[r] * v[r];
      }
      f32x4 vl = *(f32x4*)&OL[s][c * 256 + lane * 4];
#pragma unroll
      for (int r = 0; r < 4; ++r)
        olv[c][r] = eor[r] * olv[c][r] + esr[r] * vl[r];
    }
  };

  if (wid == 1) write_slot(0);
  if (wid == 3) write_slot(1);
  __syncthreads();
  if (wid == 0) merge_slot(0);
  if (wid == 2) merge_slot(1);
  __syncthreads();
  if (wid == 2) write_slot(0);
  __syncthreads();
  if (wid == 0) {
    merge_slot(0);
    float* outp = out + (size_t)(b * SEQ + iw) * OUTC;
#pragma unroll
    for (int c = 0; c < 2; ++c) {
      float lir[4];
#pragma unroll
      for (int r = 0; r < 4; ++r) lir[r] = 1.f / olv[c][r];
#pragma unroll
      for (int n = 0; n < 8; ++n) {
        float bu = bias[n * 16 + lo];
#pragma unroll
        for (int r = 0; r < 4; ++r)
          outp[(size_t)(c * 16 + 4 * g + r) * OUTC + n * 16 + lo] =
              o[c][n][r] * lir[r] + bu;
      }
    }
  }
}

// ---------------------------------------------------------------------------
extern "C" void kernel_launch(void* const* d_in, const int* in_sizes, int n_in,
                              void* d_out, int out_size, void* d_ws, size_t ws_size,
                              hipStream_t stream) {
  (void)in_sizes; (void)n_in; (void)out_size; (void)ws_size;
  const float* x      = (const float*)d_in[0];
  const float* weight = (const float*)d_in[1];
  const float* bias   = (const float*)d_in[2];
  const float* wq     = (const float*)d_in[3];
  const float* bq     = (const float*)d_in[4];
  const float* wk     = (const float*)d_in[5];
  const float* bk     = (const float*)d_in[6];
  const float* wv     = (const float*)d_in[7];
  const float* bv     = (const float*)d_in[8];
  float* out = (float*)d_out;

  char* ws = (char*)d_ws;
  short* kbuf = (short*)(ws);                                   // 1 MiB [p][32]
  short* vfb  = (short*)(ws + ((size_t)1 << 20));               // 4 MiB VF tiles
  short* qlb  = (short*)(ws + ((size_t)5 << 20));               // 1 MiB QL tiles
  // wqb|wkb|wfT form one contiguous 48KB "wall" used by k_proj
  short* wqb  = (short*)(ws + ((size_t)6 << 20));               // 8 KiB
  short* wkb  = (short*)(ws + ((size_t)6 << 20) + 8192);        // 8 KiB
  short* wfT  = (short*)(ws + ((size_t)6 << 20) + 16384);       // 32 KiB
  float* bfu  = (float*)(ws + ((size_t)6 << 20) + 49152);       // 512 B

  hipLaunchKernelGGL(k_fuse, dim3(OUTC), dim3(CIN), 0, stream,
                     wq, wk, wv, weight, bv, wqb, wkb, wfT, bfu);
  hipLaunchKernelGGL(k_proj, dim3(NB * SEQ / 64), dim3(256), 0, stream,
                     x, bq, bk, wqb /* = wall */, bfu, qlb, kbuf, vfb);
  hipLaunchKernelGGL(k_attn, dim3(NB * SEQ / 32), dim3(256), 0, stream,
                     qlb, kbuf, vfb, bias, out);
}